// Round 13
// baseline (201.184 us; speedup 1.0000x reference)
//
#include <hip/hip_runtime.h>
#include <hip/hip_bf16.h>
#include <cmath>
#include <cstdint>

typedef unsigned int u32;
typedef unsigned char u8;
typedef unsigned short ushort;
typedef __attribute__((ext_vector_type(8))) short short8;
typedef __attribute__((ext_vector_type(4))) float f32x4;
typedef __attribute__((ext_vector_type(16))) float f32x16;
typedef __attribute__((ext_vector_type(4))) unsigned short us4;

#define Gn 2048
#define Hd 256
#define CSTRIDE 192

static __device__ __forceinline__ ushort f2bf(float x) {
    __hip_bfloat16 b = __float2bfloat16(x);
    return *reinterpret_cast<ushort*>(&b);
}
static __device__ __forceinline__ float bf2f(ushort u) {
    return __uint_as_float(((u32)u) << 16);
}
// bf16x3 split: hi = truncate, lo = rne(x - hi). Same math everywhere.
static __device__ __forceinline__ void split2(float x, ushort& h, ushort& lo) {
    const u32 bi = __float_as_uint(x);
    h = (ushort)(bi >> 16);
    lo = f2bf(x - __uint_as_float(bi & 0xffff0000u));
}

// ===========================================================================
// Weight arenas are FRAGMENT-MAJOR: a wave's MFMA B-fragment (16 cols x 32 k)
// is one contiguous 1KB burst: lane l reads [base + l*8 .. +8).
// R13: ACTIVATION PLANES — activations consumed as GEMM A-operands are stored
// as pre-split bf16 hi/lo planes (produced by LN kernels / GEMM / attention
// epilogues). GEMMs do zero split-VALU and zero LN recompute.
// ===========================================================================

// ===========================================================================
// Plane GEMM body: A from hi/lo planes. 32x64 tile, 2 waves.
// OUTMODE 1 = QKV bf16 epilogue (Q pre-scaled 1/sqrt(32)*log2e).
// QKVMODE 1 (M): V row-layout; QKVMODE 2 (S): V transposed.
// KT=512: ks>=8 reads slot2 arena. WPL: epilogue also writes hi/lo planes.
// ===========================================================================
template <int BETA, int OUTMODE, int QKVMODE, int KT, int WPL>
static __device__ __forceinline__ void gemm_pl(
    const int bx, const int by, const int bz,
    const ushort* __restrict__ ah, const ushort* __restrict__ al, int lda,
    const ushort* __restrict__ bt_hi, const ushort* __restrict__ bt_lo,
    int slot0, int slot2, const float* __restrict__ bias,
    float* __restrict__ C, int N,
    ushort* __restrict__ xh, ushort* __restrict__ xl)
{
    const int tid = threadIdx.x;
    const int wv = tid >> 6, l = tid & 63;
    const int lr = l & 15, lg = l >> 4;
    const int row = bx * 32 + wv * 16 + lr;
    const int col0 = by * 64;
    int slot = slot0, zq = 0, buf = 0;
    if (QKVMODE == 1) { slot = slot0 + bz + bz / 3; zq = bz % 3; buf = bz / 3; }
    else if (QKVMODE == 2) { slot = slot0 + bz; zq = bz; }
    const ushort* bhb = bt_hi + (long)slot * 65536;
    const ushort* blb = bt_lo + (long)slot * 65536;
    const ushort* arh = ah + (long)row * lda;
    const ushort* arl = al + (long)row * lda;

    const f32x4 z4 = {0.f, 0.f, 0.f, 0.f};
    f32x4 acc[4] = {z4, z4, z4, z4};

    #pragma unroll
    for (int ks = 0; ks < KT / 32; ++ks) {
        const int k0 = ks * 32;
        const ushort* bh; const ushort* bl; int kbi = ks;
        if (KT == 512 && k0 >= 256) {
            bh = bt_hi + (long)slot2 * 65536;
            bl = bt_lo + (long)slot2 * 65536;
            kbi = ks - 8;
        } else { bh = bhb; bl = blb; }
        const short8 ahi = *(const short8*)&arh[k0 + lg * 8];
        const short8 alo = *(const short8*)&arl[k0 + lg * 8];
        #pragma unroll
        for (int f = 0; f < 4; ++f) {
            const long bo = (long)(((by * 4 + f) * 8 + kbi) << 9) + (l << 3);
            const short8 bhi = *(const short8*)&bh[bo];
            const short8 blo = *(const short8*)&bl[bo];
            acc[f] = __builtin_amdgcn_mfma_f32_16x16x32_bf16(ahi, bhi, acc[f], 0, 0, 0);
            acc[f] = __builtin_amdgcn_mfma_f32_16x16x32_bf16(alo, bhi, acc[f], 0, 0, 0);
            acc[f] = __builtin_amdgcn_mfma_f32_16x16x32_bf16(ahi, blo, acc[f], 0, 0, 0);
        }
    }

    const float QS = 0.17677669529663687f * 1.4426950408889634f;

    #pragma unroll
    for (int f = 0; f < 4; ++f) {
        const int col = col0 + f * 16 + lr;
        const float bv = bias ? bias[col] : 0.f;
        #pragma unroll
        for (int r = 0; r < 4; ++r) {
            const int rr = bx * 32 + wv * 16 + lg * 4 + r;
            float v = acc[f][r] + bv;
            if (OUTMODE == 1) {
                if (zq == 0) v *= QS;
                ushort* ob = (ushort*)C + (long)buf * 1572864;
                const int h = col >> 5, d = col & 31;
                if (QKVMODE == 1 || zq < 2)
                    ob[zq * 524288 + ((h * 2048 + rr) << 5) + d] = f2bf(v);
                else
                    ob[1048576 + ((h * 32 + d) << 11) + rr] = f2bf(v);
            } else {
                if (BETA) v += C[(long)rr * N + col];
                C[(long)rr * N + col] = v;
                if (WPL) {
                    ushort hh, ll;
                    split2(v, hh, ll);
                    xh[(long)rr * 256 + col] = hh;
                    xl[(long)rr * 256 + col] = ll;
                }
            }
        }
    }
}

// fp32-A GEMM body (preGEMM1 only: gene_emb input): split in-kernel.
static __device__ __forceinline__ void gemm_f32a(
    const int bx, const int by,
    const float* __restrict__ A, int lda,
    const ushort* __restrict__ bt_hi, const ushort* __restrict__ bt_lo,
    int slot, const float* __restrict__ bias, float* __restrict__ C, int N)
{
    const int tid = threadIdx.x;
    const int wv = tid >> 6, l = tid & 63;
    const int lr = l & 15, lg = l >> 4;
    const int row = bx * 32 + wv * 16 + lr;
    const int col0 = by * 64;
    const ushort* bhb = bt_hi + (long)slot * 65536;
    const ushort* blb = bt_lo + (long)slot * 65536;
    const float* arow = A + (long)row * lda;

    const f32x4 z4 = {0.f, 0.f, 0.f, 0.f};
    f32x4 acc[4] = {z4, z4, z4, z4};

    #pragma unroll
    for (int ks = 0; ks < 8; ++ks) {
        const int k0 = ks * 32;
        float av[8];
        *(float4*)&av[0] = *(const float4*)&arow[k0 + lg * 8];
        *(float4*)&av[4] = *(const float4*)&arow[k0 + lg * 8 + 4];
        short8 ahi, alo;
        #pragma unroll
        for (int j = 0; j < 8; ++j) {
            ushort hh, ll;
            split2(av[j], hh, ll);
            ahi[j] = (short)hh; alo[j] = (short)ll;
        }
        #pragma unroll
        for (int f = 0; f < 4; ++f) {
            const long bo = (long)(((by * 4 + f) * 8 + ks) << 9) + (l << 3);
            const short8 bhi = *(const short8*)&bhb[bo];
            const short8 blo = *(const short8*)&blb[bo];
            acc[f] = __builtin_amdgcn_mfma_f32_16x16x32_bf16(ahi, bhi, acc[f], 0, 0, 0);
            acc[f] = __builtin_amdgcn_mfma_f32_16x16x32_bf16(alo, bhi, acc[f], 0, 0, 0);
            acc[f] = __builtin_amdgcn_mfma_f32_16x16x32_bf16(ahi, blo, acc[f], 0, 0, 0);
        }
    }
    #pragma unroll
    for (int f = 0; f < 4; ++f) {
        const int col = col0 + f * 16 + lr;
        const float bv = bias[col];
        #pragma unroll
        for (int r = 0; r < 4; ++r) {
            const int rr = bx * 32 + wv * 16 + lg * 4 + r;
            C[(long)rr * N + col] = acc[f][r] + bv;
        }
    }
}

// ===========================================================================
// LayerNorm (+relu) -> split planes (+optional fp32 dup). One wave per row.
// ===========================================================================
template <int RELU, int DUP>
__global__ __launch_bounds__(64) void ln_pl_kernel(
    const float* __restrict__ X, const float* __restrict__ gw,
    const float* __restrict__ bw, ushort* __restrict__ Yh,
    ushort* __restrict__ Yl, float* __restrict__ Y2)
{
    const int row = blockIdx.x, tid = threadIdx.x;
    const float4 x = *(const float4*)&X[(long)row * 256 + (tid << 2)];
    float s = x.x + x.y + x.z + x.w;
    float s2 = x.x * x.x + x.y * x.y + x.z * x.z + x.w * x.w;
    #pragma unroll
    for (int o = 1; o < 64; o <<= 1) { s += __shfl_xor(s, o); s2 += __shfl_xor(s2, o); }
    const float mean = s * (1.f / 256.f);
    const float var = s2 * (1.f / 256.f) - mean * mean;
    const float rs = rsqrtf(var + 1e-5f);
    const float4 g4 = *(const float4*)&gw[tid << 2];
    const float4 b4 = *(const float4*)&bw[tid << 2];
    float y[4];
    y[0] = (x.x - mean) * rs * g4.x + b4.x;
    y[1] = (x.y - mean) * rs * g4.y + b4.y;
    y[2] = (x.z - mean) * rs * g4.z + b4.z;
    y[3] = (x.w - mean) * rs * g4.w + b4.w;
    us4 h4, l4;
    #pragma unroll
    for (int j = 0; j < 4; ++j) {
        if (RELU) y[j] = fmaxf(y[j], 0.f);
        ushort hh, ll;
        split2(y[j], hh, ll);
        h4[j] = hh; l4[j] = ll;
    }
    *(us4*)&Yh[(long)row * 256 + (tid << 2)] = h4;
    *(us4*)&Yl[(long)row * 256 + (tid << 2)] = l4;
    if (DUP) {
        float4 yo; yo.x = y[0]; yo.y = y[1]; yo.z = y[2]; yo.w = y[3];
        *(float4*)&Y2[(long)row * 256 + (tid << 2)] = yo;
    }
}

// ===========================================================================
// Merged A (256 thr, grid 192): blocks 0-63 mask-dtype detect; blocks 64-191
// weight pre-split (fragment-major). Block 0 also zeroes the wsum ticket.
// ===========================================================================
__global__ __launch_bounds__(256) void mergedA_kernel(
    const u8* __restrict__ adj, int* __restrict__ det0, int* __restrict__ det1,
    const float* __restrict__ pre_w1, const float* __restrict__ pre_w2,
    const float* __restrict__ wm, const float* __restrict__ wsw,
    const float* __restrict__ gate_w1, const float* __restrict__ tr_w,
    ushort* __restrict__ bt_hi, ushort* __restrict__ bt_lo,
    u32* __restrict__ ticket)
{
    __shared__ float T[32][257];
    __shared__ int sd0[4], sd1[4];
    const int tid = threadIdx.x;
    if (blockIdx.x == 0 && tid == 0) *ticket = 0;
    if (blockIdx.x < 64) {
        const int idx = blockIdx.x * 256 + tid;
        const uint4 w = ((const uint4*)adj)[idx];
        int c0 = ((w.x & 0xffu) ? 1 : 0) + ((w.y & 0xffu) ? 1 : 0) +
                 ((w.z & 0xffu) ? 1 : 0) + ((w.w & 0xffu) ? 1 : 0);
        int c1 = ((w.x & 0xffffff00u) ? 1 : 0) + ((w.y & 0xffffff00u) ? 1 : 0) +
                 ((w.z & 0xffffff00u) ? 1 : 0) + ((w.w & 0xffffff00u) ? 1 : 0);
        #pragma unroll
        for (int o = 1; o < 64; o <<= 1) { c0 += __shfl_xor(c0, o); c1 += __shfl_xor(c1, o); }
        if ((tid & 63) == 0) { sd0[tid >> 6] = c0; sd1[tid >> 6] = c1; }
        __syncthreads();
        if (tid == 0) {
            det0[blockIdx.x] = sd0[0] + sd0[1] + sd0[2] + sd0[3];
            det1[blockIdx.x] = sd1[0] + sd1[1] + sd1[2] + sd1[3];
        }
        return;
    }
    const int b2 = blockIdx.x - 64;
    const int slot = b2 >> 3;
    const int kb = b2 & 7;
    const int k0 = kb * 32;
    const float* src; int ncols = 256;
    if (slot == 0) src = pre_w1;
    else if (slot == 1) src = pre_w2;
    else if (slot < 6) src = wm + (long)(slot - 2) * 65536;
    else if (slot < 10) src = wm + (long)(4 + slot - 6) * 65536;
    else if (slot < 14) src = wsw + (long)(slot - 10) * 65536;
    else if (slot == 14) { src = gate_w1; ncols = 128; }
    else src = tr_w;

    const int lsh = (ncols == 256) ? 6 : 5;
    const int tot = 32 << lsh;
    for (int i = tid; i < tot; i += 256) {
        const int kk = i >> lsh, c4 = (i & ((1 << lsh) - 1)) << 2;
        const float4 v = *(const float4*)&src[(long)(k0 + kk) * ncols + c4];
        T[kk][c4 + 0] = v.x; T[kk][c4 + 1] = v.y;
        T[kk][c4 + 2] = v.z; T[kk][c4 + 3] = v.w;
    }
    __syncthreads();
    if (tid < ncols) {
        ushort hb[32], lb[32];
        #pragma unroll
        for (int kk = 0; kk < 32; ++kk) split2(T[kk][tid], hb[kk], lb[kk]);
        const int cb = tid >> 4, lr = tid & 15;
        const long base = (long)slot * 65536 + ((cb * 8 + kb) << 9);
        ushort* oh = bt_hi + base;
        ushort* ol = bt_lo + base;
        #pragma unroll
        for (int lg2 = 0; lg2 < 4; ++lg2) {
            const int off = (lg2 * 16 + lr) << 3;
            *(uint4*)&oh[off] = *(const uint4*)&hb[lg2 * 8];
            *(uint4*)&ol[off] = *(const uint4*)&lb[lg2 * 8];
        }
    }
}

// ===========================================================================
// Merged B (128 thr, grid 2304): blocks 0-2047 pack masks + CSR for their 2
// rows; blocks 2048-2303 preGEMM1 (tmp0 = gene_emb @ pre_w1 + b1, fp32 A).
// ===========================================================================
__global__ __launch_bounds__(128) void mergedB_kernel(
    const u8* __restrict__ src0, const u8* __restrict__ src1,
    const int* __restrict__ det0, const int* __restrict__ det1,
    u32* __restrict__ bits, int* __restrict__ deg, int* __restrict__ colidx,
    const float* __restrict__ gene_emb,
    const ushort* __restrict__ bt_hi, const ushort* __restrict__ bt_lo,
    const float* __restrict__ pre_b1, float* __restrict__ tmp0)
{
    __shared__ u32 sw[128];
    const int tid = threadIdx.x;
    if (blockIdx.x < 2048) {
        const int lane = tid & 63;
        int c0 = det0[lane], c1 = det1[lane];
        #pragma unroll
        for (int o = 1; o < 64; o <<= 1) { c0 += __shfl_xor(c0, o); c1 += __shfl_xor(c1, o); }
        const int f = (c0 > 0) ? ((c1 > 0) ? 1 : 0) : 2;
        const int W = blockIdx.x * 128 + tid;
        const int z = W >> 17;
        const int rem = W & 131071;
        const int row = rem >> 6, w = rem & 63;
        const u8* src = z ? src1 : src0;
        u32 v = 0;
        if (f == 1) {
            const uint4* p = (const uint4*)(src + (long)row * 2048 + w * 32);
            const uint4 q0 = p[0], q1 = p[1];
            const u32 ws8[8] = {q0.x, q0.y, q0.z, q0.w, q1.x, q1.y, q1.z, q1.w};
            #pragma unroll
            for (int j = 0; j < 8; ++j) {
                const u32 x = ws8[j];
                const u32 m = (((x & 0x7f7f7f7fu) + 0x7f7f7f7fu) | x) & 0x80808080u;
                const u32 b4 = ((m >> 7) & 1u) | ((m >> 14) & 2u) |
                               ((m >> 21) & 4u) | ((m >> 28) & 8u);
                v |= b4 << (j * 4);
            }
        } else if (f == 0) {
            const uint4* p = (const uint4*)((const int*)src + (long)row * 2048 + w * 32);
            #pragma unroll
            for (int j = 0; j < 8; ++j) {
                const uint4 q = p[j];
                v |= (q.x ? 1u : 0u) << (j * 4 + 0);
                v |= (q.y ? 1u : 0u) << (j * 4 + 1);
                v |= (q.z ? 1u : 0u) << (j * 4 + 2);
                v |= (q.w ? 1u : 0u) << (j * 4 + 3);
            }
        } else {
            const uint4* p = (const uint4*)((const float*)src + (long)row * 2048 + w * 32);
            #pragma unroll
            for (int j = 0; j < 8; ++j) {
                const uint4 q = p[j];
                v |= ((q.x & 0x7fffffffu) ? 1u : 0u) << (j * 4 + 0);
                v |= ((q.y & 0x7fffffffu) ? 1u : 0u) << (j * 4 + 1);
                v |= ((q.z & 0x7fffffffu) ? 1u : 0u) << (j * 4 + 2);
                v |= ((q.w & 0x7fffffffu) ? 1u : 0u) << (j * 4 + 3);
            }
        }
        bits[(long)z * 131072 + rem] = v;
        sw[tid] = v;
        __syncthreads();
        if (tid < 2) {
            const int rem0 = (blockIdx.x * 128) & 131071;
            const int r = (rem0 >> 6) + tid;
            int* ci = colidx + ((long)z * 2048 + r) * CSTRIDE;
            int d = 0;
            #pragma unroll 4
            for (int ww = 0; ww < 64; ++ww) {
                u32 x = sw[tid * 64 + ww];
                while (x) {
                    const int j = __ffs(x) - 1;
                    if (d < CSTRIDE) ci[d] = ww * 32 + j;
                    ++d;
                    x &= x - 1;
                }
            }
            deg[z * 2048 + r] = d < CSTRIDE ? d : CSTRIDE;
        }
        return;
    }
    const int b2 = blockIdx.x - 2048;
    gemm_f32a(b2 >> 2, b2 & 3, gene_emb, 256, bt_hi, bt_lo, 0, pre_b1, tmp0, 256);
}

// GEMM wrappers (plane A) ----------------------------------------------------
__global__ __launch_bounds__(128) void gemm2_kernel(      // tmp1 = A1 @ w2 + b2
    const ushort* __restrict__ a1h, const ushort* __restrict__ a1l,
    const ushort* __restrict__ bt_hi, const ushort* __restrict__ bt_lo,
    const float* __restrict__ pre_b2, float* __restrict__ tmp1)
{
    gemm_pl<0, 0, 0, 256, 0>(blockIdx.x, blockIdx.y, 0, a1h, a1l, 256,
                             bt_hi, bt_lo, 1, 0, pre_b2, tmp1, 256, nullptr, nullptr);
}
__global__ __launch_bounds__(128) void qkvm_kernel(
    const ushort* __restrict__ a2h, const ushort* __restrict__ a2l,
    const ushort* __restrict__ bt_hi, const ushort* __restrict__ bt_lo,
    float* __restrict__ qkvb)
{
    gemm_pl<0, 1, 1, 256, 0>(blockIdx.x, blockIdx.y, blockIdx.z, a2h, a2l, 256,
                             bt_hi, bt_lo, 2, 0, nullptr, qkvb, 256, nullptr, nullptr);
}
__global__ __launch_bounds__(128) void wo_m_kernel(       // xg1 += ctx@Wo (dual), emit planes
    const ushort* __restrict__ c2h, const ushort* __restrict__ c2l,
    const ushort* __restrict__ bt_hi, const ushort* __restrict__ bt_lo,
    float* __restrict__ xg1, ushort* __restrict__ x1h, ushort* __restrict__ x1l)
{
    gemm_pl<1, 0, 0, 512, 1>(blockIdx.x, blockIdx.y, 0, c2h, c2l, 512,
                             bt_hi, bt_lo, 5, 9, nullptr, xg1, 256, x1h, x1l);
}
__global__ __launch_bounds__(128) void qkvs_kernel(
    const ushort* __restrict__ x1h, const ushort* __restrict__ x1l,
    const ushort* __restrict__ bt_hi, const ushort* __restrict__ bt_lo,
    float* __restrict__ qkvb)
{
    gemm_pl<0, 1, 2, 256, 0>(blockIdx.x, blockIdx.y, blockIdx.z, x1h, x1l, 256,
                             bt_hi, bt_lo, 10, 0, nullptr, qkvb, 256, nullptr, nullptr);
}
__global__ __launch_bounds__(128) void wo_s_kernel(
    const ushort* __restrict__ c2h, const ushort* __restrict__ c2l,
    const ushort* __restrict__ bt_hi, const ushort* __restrict__ bt_lo,
    float* __restrict__ xg1)
{
    gemm_pl<1, 0, 0, 256, 0>(blockIdx.x, blockIdx.y, 0, c2h, c2l, 512,
                             bt_hi, bt_lo, 13, 0, nullptr, xg1, 256, nullptr, nullptr);
}

// ===========================================================================
// Sparse masked attention (M block), exp2 domain. One wave per (row, graph).
// Writes ctx hi/lo planes.
// ===========================================================================
__global__ __launch_bounds__(64) void attn_sparse_kernel(
    const ushort* __restrict__ qkvb, const int* __restrict__ deg,
    const int* __restrict__ colidx, ushort* __restrict__ ch, ushort* __restrict__ cl)
{
    const int r = blockIdx.x, z = blockIdx.y;
    const ushort* qb = qkvb + (long)z * 1572864;
    const ushort* kb = qb + 524288;
    const ushort* vr = qb + 1048576;
    const int l = threadIdx.x;
    const int h = l >> 3, dg = l & 7;
    const long ooff = (long)r * 512 + z * 256 + h * 32 + dg * 4;
    const int n = deg[z * 2048 + r];
    float o[4];
    if (n == 0) {
        float a0 = 0.f, a1 = 0.f, a2 = 0.f, a3 = 0.f;
        for (int k = 0; k < 2048; ++k) {
            const us4 vv = *(const us4*)&vr[((h * 2048 + k) << 5) + dg * 4];
            a0 += bf2f(vv[0]); a1 += bf2f(vv[1]); a2 += bf2f(vv[2]); a3 += bf2f(vv[3]);
        }
        const float inv = 1.f / 2048.f;
        o[0] = a0 * inv; o[1] = a1 * inv; o[2] = a2 * inv; o[3] = a3 * inv;
    } else {
        float q0, q1, q2, q3;
        {
            const us4 qv = *(const us4*)&qb[((h * 2048 + r) << 5) + dg * 4];
            q0 = bf2f(qv[0]); q1 = bf2f(qv[1]); q2 = bf2f(qv[2]); q3 = bf2f(qv[3]);
        }
        const int* ci = colidx + ((long)z * 2048 + r) * CSTRIDE;
        float m = -INFINITY, lsum = 0.f;
        float a0 = 0.f, a1 = 0.f, a2 = 0.f, a3 = 0.f;
        int kn = ci[0];
        us4 kv = *(const us4*)&kb[((h * 2048 + kn) << 5) + dg * 4];
        us4 vv = *(const us4*)&vr[((h * 2048 + kn) << 5) + dg * 4];
        for (int e = 0; e < n; ++e) {
            const us4 kc = kv, vc = vv;
            if (e + 1 < n) {
                kn = ci[e + 1];
                kv = *(const us4*)&kb[((h * 2048 + kn) << 5) + dg * 4];
                vv = *(const us4*)&vr[((h * 2048 + kn) << 5) + dg * 4];
            }
            float s = q0 * bf2f(kc[0]) + q1 * bf2f(kc[1]) +
                      q2 * bf2f(kc[2]) + q3 * bf2f(kc[3]);
            s += __shfl_xor(s, 1); s += __shfl_xor(s, 2); s += __shfl_xor(s, 4);
            const float mn = fmaxf(m, s);
            const float fac = __builtin_amdgcn_exp2f(m - mn);
            const float p = __builtin_amdgcn_exp2f(s - mn);
            lsum = lsum * fac + p;
            a0 = a0 * fac + p * bf2f(vc[0]);
            a1 = a1 * fac + p * bf2f(vc[1]);
            a2 = a2 * fac + p * bf2f(vc[2]);
            a3 = a3 * fac + p * bf2f(vc[3]);
            m = mn;
        }
        const float inv = 1.f / lsum;
        o[0] = a0 * inv; o[1] = a1 * inv; o[2] = a2 * inv; o[3] = a3 * inv;
    }
    us4 h4, l4;
    #pragma unroll
    for (int j = 0; j < 4; ++j) { ushort hh, ll; split2(o[j], hh, ll); h4[j] = hh; l4[j] = ll; }
    *(us4*)&ch[ooff] = h4;
    *(us4*)&cl[ooff] = l4;
}

// ===========================================================================
// Dense attention (S block): 32x32x16 swapped MFMA, in-register P, exp2,
// k-split x8 (512 thr), parallel 8-way merge, plane output.
// ===========================================================================
__global__ __launch_bounds__(512) void attn_dense_kernel(
    const ushort* __restrict__ qkvb, ushort* __restrict__ ch, ushort* __restrict__ cl)
{
    const ushort* qb = qkvb;
    const ushort* kb = qb + 524288;
    const ushort* vt = qb + 1048576;
    const int h = blockIdx.x, qt = blockIdx.y;
    const int wv = threadIdx.x >> 6;
    const int l = threadIdx.x & 63;
    const int lq = l & 31;
    const int hi = l >> 5;
    const int qglob = qt * 32 + lq;

    __shared__ float Mm[8][32], Ml[8][32];
    __shared__ float Macc[8][64][17];
    __shared__ float ctile[32][33];

    const int qoff = ((h * 2048 + qglob) << 5) + hi * 8;
    const short8 qf0 = *(const short8*)&qb[qoff];
    const short8 qf1 = *(const short8*)&qb[qoff + 16];

    float m = -INFINITY, lsum = 0.f;
    f32x16 acc, zz16;
    #pragma unroll
    for (int i = 0; i < 16; ++i) { acc[i] = 0.f; zz16[i] = 0.f; }

    const int kt0 = wv * 256;
    #pragma unroll 2
    for (int it = 0; it < 8; ++it) {
        const int kbase = kt0 + it * 32;
        const int koff = ((h * 2048 + kbase + lq) << 5) + hi * 8;
        const short8 kf0 = *(const short8*)&kb[koff];
        const short8 kf1 = *(const short8*)&kb[koff + 16];
        f32x16 s = __builtin_amdgcn_mfma_f32_32x32x16_bf16(kf0, qf0, zz16, 0, 0, 0);
        s = __builtin_amdgcn_mfma_f32_32x32x16_bf16(kf1, qf1, s, 0, 0, 0);
        float sc[16];
        #pragma unroll
        for (int i = 0; i < 16; ++i) sc[i] = s[i];
        float t[8];
        #pragma unroll
        for (int i = 0; i < 8; ++i) t[i] = fmaxf(sc[i], sc[i + 8]);
        #pragma unroll
        for (int i = 0; i < 4; ++i) t[i] = fmaxf(t[i], t[i + 4]);
        float mt = fmaxf(fmaxf(t[0], t[1]), fmaxf(t[2], t[3]));
        mt = fmaxf(mt, __shfl_xor(mt, 32));
        const float mn = fmaxf(m, mt);
        if (__ballot(mn != m)) {
            const float fac = __builtin_amdgcn_exp2f(m - mn);
            lsum *= fac;
            #pragma unroll
            for (int i = 0; i < 16; ++i) acc[i] *= fac;
            m = mn;
        }
        #pragma unroll
        for (int i = 0; i < 16; ++i) sc[i] = __builtin_amdgcn_exp2f(sc[i] - m);
        #pragma unroll
        for (int i = 0; i < 8; ++i) t[i] = sc[i] + sc[i + 8];
        #pragma unroll
        for (int i = 0; i < 4; ++i) t[i] = t[i] + t[i + 4];
        float ps = (t[0] + t[1]) + (t[2] + t[3]);
        ps += __shfl_xor(ps, 32);
        lsum += ps;
        u32 pk[8];
        #pragma unroll
        for (int g = 0; g < 4; ++g) {
            asm("v_cvt_pk_bf16_f32 %0, %1, %2"
                : "=v"(pk[2 * g]) : "v"(sc[4 * g + 0]), "v"(sc[4 * g + 1]));
            asm("v_cvt_pk_bf16_f32 %0, %1, %2"
                : "=v"(pk[2 * g + 1]) : "v"(sc[4 * g + 2]), "v"(sc[4 * g + 3]));
        }
        asm volatile("v_permlane32_swap_b32 %0, %1" : "+v"(pk[0]), "+v"(pk[2]));
        asm volatile("v_permlane32_swap_b32 %0, %1" : "+v"(pk[1]), "+v"(pk[3]));
        asm volatile("v_permlane32_swap_b32 %0, %1" : "+v"(pk[4]), "+v"(pk[6]));
        asm volatile("v_permlane32_swap_b32 %0, %1" : "+v"(pk[5]), "+v"(pk[7]));
        short8 pB0, pB1;
        ((u32*)&pB0)[0] = pk[0]; ((u32*)&pB0)[1] = pk[1];
        ((u32*)&pB0)[2] = pk[2]; ((u32*)&pB0)[3] = pk[3];
        ((u32*)&pB1)[0] = pk[4]; ((u32*)&pB1)[1] = pk[5];
        ((u32*)&pB1)[2] = pk[6]; ((u32*)&pB1)[3] = pk[7];
        const int voff = ((h * 32 + lq) << 11) + kbase + hi * 8;
        const short8 vf0 = *(const short8*)&vt[voff];
        const short8 vf1 = *(const short8*)&vt[voff + 16];
        acc = __builtin_amdgcn_mfma_f32_32x32x16_bf16(vf0, pB0, acc, 0, 0, 0);
        acc = __builtin_amdgcn_mfma_f32_32x32x16_bf16(vf1, pB1, acc, 0, 0, 0);
    }

    if (l < 32) { Mm[wv][l] = m; Ml[wv][l] = lsum; }
    #pragma unroll
    for (int i = 0; i < 16; ++i) Macc[wv][l][i] = acc[i];
    __syncthreads();
    {
        const int t = threadIdx.x;
        const int q = t & 31, j = t >> 5;
        float M = Mm[0][q];
        #pragma unroll
        for (int w = 1; w < 8; ++w) M = fmaxf(M, Mm[w][q]);
        float fw[8], den = 0.f;
        #pragma unroll
        for (int w = 0; w < 8; ++w) {
            fw[w] = __builtin_amdgcn_exp2f(Mm[w][q] - M);
            den += Ml[w][q] * fw[w];
        }
        const float inv = 1.f / den;
        #pragma unroll
        for (int half = 0; half < 2; ++half) {
            const int d = j + 16 * half;
            const int i = (d & 3) | ((d >> 3) << 2);
            const int h2 = (d >> 2) & 1;
            float o = 0.f;
            #pragma unroll
            for (int w = 0; w < 8; ++w) o += Macc[w][h2 * 32 + q][i] * fw[w];
            ctile[d][q] = o * inv;
        }
    }
    __syncthreads();
    if (threadIdx.x < 256) {
        const int t = threadIdx.x;
        const int q = t >> 3, d0 = (t & 7) << 2;
        us4 h4, l4;
        #pragma unroll
        for (int j = 0; j < 4; ++j) {
            ushort hh, ll;
            split2(ctile[d0 + j][q], hh, ll);
            h4[j] = hh; l4[j] = ll;
        }
        const long ooff = (long)(qt * 32 + q) * 512 + h * 32 + d0;
        *(us4*)&ch[ooff] = h4;
        *(us4*)&cl[ooff] = l4;
    }
}

// ===========================================================================
// Aggregation GEMM (plane A, no LN): y<8 -> t tile; y==8 -> in-register gate.
// ===========================================================================
__global__ __launch_bounds__(64) void aggr_gemm_kernel(
    const ushort* __restrict__ a3h, const ushort* __restrict__ a3l,
    const ushort* __restrict__ bt_hi, const ushort* __restrict__ bt_lo,
    const float* __restrict__ tr_b, const float* __restrict__ g_b1,
    const float* __restrict__ g_w2, const float* __restrict__ g_b2,
    float* __restrict__ t_out, float* __restrict__ gv)
{
    const int l = threadIdx.x;
    const int lr = l & 15, lg = l >> 4;
    const int row0 = blockIdx.x * 16;
    const int gate = (blockIdx.y == 8);
    const int slot = gate ? 14 : 15;
    const int col0 = gate ? 0 : blockIdx.y * 32;
    const int NF = gate ? 8 : 2;
    const ushort* bh0 = bt_hi + (long)slot * 65536;
    const ushort* bl0 = bt_lo + (long)slot * 65536;
    const ushort* arh = a3h + (long)(row0 + lr) * 256;
    const ushort* arl = a3l + (long)(row0 + lr) * 256;

    const f32x4 z4 = {0.f, 0.f, 0.f, 0.f};
    f32x4 acc[8] = {z4, z4, z4, z4, z4, z4, z4, z4};

    #pragma unroll
    for (int ks = 0; ks < 8; ++ks) {
        const int k0 = ks * 32;
        const short8 ahi = *(const short8*)&arh[k0 + lg * 8];
        const short8 alo = *(const short8*)&arl[k0 + lg * 8];
        for (int f = 0; f < NF; ++f) {
            const int cb = gate ? f : ((int)blockIdx.y * 2 + f);
            const long bo = (long)((cb * 8 + ks) << 9) + (l << 3);
            const short8 bhi = *(const short8*)&bh0[bo];
            const short8 blo = *(const short8*)&bl0[bo];
            acc[f] = __builtin_amdgcn_mfma_f32_16x16x32_bf16(ahi, bhi, acc[f], 0, 0, 0);
            acc[f] = __builtin_amdgcn_mfma_f32_16x16x32_bf16(alo, bhi, acc[f], 0, 0, 0);
            acc[f] = __builtin_amdgcn_mfma_f32_16x16x32_bf16(ahi, blo, acc[f], 0, 0, 0);
        }
    }

    if (!gate) {
        #pragma unroll
        for (int f = 0; f < 2; ++f) {
            const int col = col0 + f * 16 + lr;
            const float bv = tr_b[col];
            #pragma unroll
            for (int r = 0; r < 4; ++r) {
                const int rr = row0 + lg * 4 + r;
                t_out[(long)rr * 256 + col] = fmaxf(acc[f][r] + bv, 0.f);
            }
        }
    } else {
        float b1v[8], w2v[8];
        #pragma unroll
        for (int f = 0; f < 8; ++f) {
            b1v[f] = g_b1[f * 16 + lr];
            w2v[f] = g_w2[f * 16 + lr];
        }
        const float b2 = g_b2[0];
        #pragma unroll
        for (int r = 0; r < 4; ++r) {
            float t = 0.f;
            #pragma unroll
            for (int f = 0; f < 8; ++f)
                t += fmaxf(acc[f][r] + b1v[f], 0.f) * w2v[f];
            #pragma unroll
            for (int o = 1; o < 16; o <<= 1) t += __shfl_xor(t, o);
            if (lr == 0) gv[row0 + lg * 4 + r] = t + b2;
        }
    }
}

// ===========================================================================
// wsum + head (last-block finisher)
// ===========================================================================
__global__ __launch_bounds__(256) void wsum_head_kernel(
    const float* __restrict__ gv, const float* __restrict__ t,
    float* __restrict__ partial, float* __restrict__ denp, float* __restrict__ mpart,
    const float* __restrict__ hw, const float* __restrict__ hb,
    float* __restrict__ out, u32* __restrict__ ticket)
{
    const float L2E = 1.4426950408889634f;
    const int b = blockIdx.x, tid = threadIdx.x;
    float M = -INFINITY;
    #pragma unroll
    for (int i = 0; i < 32; ++i) M = fmaxf(M, gv[b * 32 + i]);
    float s = 0.f, den = 0.f;
    #pragma unroll 4
    for (int i = 0; i < 32; ++i) {
        const int r = b * 32 + i;
        const float w = __builtin_amdgcn_exp2f((gv[r] - M) * L2E);
        den += w;
        s += w * t[(long)r * 256 + tid];
    }
    partial[b * 256 + tid] = s;
    if (tid == 0) { denp[b] = den; mpart[b] = M; }
    __threadfence();
    __syncthreads();
    __shared__ int lastFlag;
    if (tid == 0) lastFlag = (atomicAdd(ticket, 1u) == 63u) ? 1 : 0;
    __syncthreads();
    if (!lastFlag) return;
    __threadfence();

    __shared__ float fb[64];
    __shared__ float dtot;
    __shared__ float red0[4], red1[4];
    if (tid < 64) {
        const float mb = mpart[tid];
        float Mg = mb;
        #pragma unroll
        for (int o = 1; o < 64; o <<= 1) Mg = fmaxf(Mg, __shfl_xor(Mg, o));
        const float f = __builtin_amdgcn_exp2f((mb - Mg) * L2E);
        fb[tid] = f;
        float dv = f * denp[tid];
        #pragma unroll
        for (int o = 1; o < 64; o <<= 1) dv += __shfl_xor(dv, o);
        if (tid == 0) dtot = dv;
    }
    __syncthreads();
    float p = 0.f;
    #pragma unroll 8
    for (int bb = 0; bb < 64; ++bb) p += fb[bb] * partial[bb * 256 + tid];
    p /= dtot;
    float s0 = p * hw[tid * 2 + 0];
    float s1 = p * hw[tid * 2 + 1];
    #pragma unroll
    for (int o = 1; o < 64; o <<= 1) { s0 += __shfl_xor(s0, o); s1 += __shfl_xor(s1, o); }
    if ((tid & 63) == 0) { red0[tid >> 6] = s0; red1[tid >> 6] = s1; }
    __syncthreads();
    if (tid == 0) {
        out[0] = red0[0] + red0[1] + red0[2] + red0[3] + hb[0];
        out[1] = red1[0] + red1[1] + red1[2] + red1[3] + hb[1];
    }
}

// ---------------------------------------------------------------------------
extern "C" void kernel_launch(void* const* d_in, const int* in_sizes, int n_in,
                              void* d_out, int out_size, void* d_ws, size_t ws_size,
                              hipStream_t stream)
{
    (void)in_sizes; (void)n_in; (void)out_size; (void)ws_size;
    const float* gene_emb = (const float*)d_in[0];
    const float* pre_w1   = (const float*)d_in[3];
    const float* pre_b1   = (const float*)d_in[4];
    const float* pre_w2   = (const float*)d_in[5];
    const float* pre_b2   = (const float*)d_in[6];
    const float* pre_ln_g = (const float*)d_in[7];
    const float* pre_ln_b = (const float*)d_in[8];
    const float* wm       = (const float*)d_in[9];
    const float* wsw      = (const float*)d_in[10];
    const float* ln_g     = (const float*)d_in[11];
    const float* ln_b     = (const float*)d_in[12];
    const float* gate_w1  = (const float*)d_in[13];
    const float* gate_b1  = (const float*)d_in[14];
    const float* gate_w2  = (const float*)d_in[15];
    const float* gate_b2  = (const float*)d_in[16];
    const float* tr_w     = (const float*)d_in[17];
    const float* tr_b     = (const float*)d_in[18];
    const float* head_w   = (const float*)d_in[19];
    const float* head_b   = (const float*)d_in[20];
    const u8* adj_pp      = (const u8*)d_in[21];
    const u8* adj_rr      = (const u8*)d_in[22];
    // d_in[1],[2],[23],[24] dead (reaction/metab branches never reach output)

    const long NHf = (long)Gn * Hd;
    float* tmp0    = (float*)d_ws;          // preG1 out (fp32), later t-matrix
    float* tmp1    = tmp0 + NHf;            // preG2 out (fp32)
    float* xg1     = tmp1 + NHf;            // residual accumulator (fp32)
    float* gv      = xg1 + NHf;             // [2048]
    float* partial = gv + Gn;               // [64][256]
    float* denp    = partial + 64 * 256;
    float* mpart   = denp + 64;
    int* det0      = (int*)(mpart + 64);
    int* det1      = det0 + 64;
    u32* ticket    = (u32*)(det1 + 64);
    int* deg       = (int*)(ticket + 64);
    int* colidx    = deg + 4096;
    u32* bits      = (u32*)(colidx + 2L * 2048 * CSTRIDE);
    ushort* qkvb   = (ushort*)(bits + 262144);     // 2 x 1572864 bf16
    ushort* bt_hi  = qkvb + 2L * 1572864;          // 16 slots x 65536
    ushort* bt_lo  = bt_hi + 16L * 65536;
    ushort* a1h    = bt_lo + 16L * 65536;          // planes [2048][256]
    ushort* a1l    = a1h + NHf;
    ushort* a2h    = a1l + NHf;
    ushort* a2l    = a2h + NHf;
    ushort* x1h    = a2l + NHf;
    ushort* x1l    = x1h + NHf;
    ushort* a3h    = x1l + NHf;
    ushort* a3l    = a3h + NHf;
    ushort* c2h    = a3l + NHf;                    // ctx planes [2048][512]
    ushort* c2l    = c2h + 2 * NHf;

    dim3 B256(256), B128(128), T64(64);
    dim3 LN(2048);

    // 1: detect || weight pre-split (also zeroes the wsum ticket)
    mergedA_kernel<<<dim3(192), B256, 0, stream>>>(adj_pp, det0, det1,
        pre_w1, pre_w2, wm, wsw, gate_w1, tr_w, bt_hi, bt_lo, ticket);
    // 2: pack masks + CSR || preGEMM1 (fp32 A)
    mergedB_kernel<<<dim3(2304), B128, 0, stream>>>(adj_pp, adj_rr, det0, det1,
        bits, deg, colidx, gene_emb, bt_hi, bt_lo, pre_b1, tmp0);
    // 3: LN1 + relu -> A1 planes
    ln_pl_kernel<1, 0><<<LN, T64, 0, stream>>>(tmp0, pre_ln_g, pre_ln_b, a1h, a1l, nullptr);
    // 4: preGEMM2 (plane A)
    gemm2_kernel<<<dim3(64, 4), B128, 0, stream>>>(a1h, a1l, bt_hi, bt_lo, pre_b2, tmp1);
    // 5: LN2 + relu -> A2 planes + xg1 fp32 dup
    ln_pl_kernel<1, 1><<<LN, T64, 0, stream>>>(tmp1, pre_ln_g, pre_ln_b, a2h, a2l, xg1);
    // 6: QKV-M (plane A, z=6)
    qkvm_kernel<<<dim3(64, 4, 6), B128, 0, stream>>>(a2h, a2l, bt_hi, bt_lo, (float*)qkvb);
    // 7: sparse masked attention -> ctx planes
    attn_sparse_kernel<<<dim3(2048, 2), T64, 0, stream>>>(qkvb, deg, colidx, c2h, c2l);
    // 8: fused dual-Wo (K=512), accumulate xg1 + emit xg1 planes
    wo_m_kernel<<<dim3(64, 4), B128, 0, stream>>>(c2h, c2l, bt_hi, bt_lo, xg1, x1h, x1l);
    // 9: QKV-S (plane A)
    qkvs_kernel<<<dim3(64, 4, 3), B128, 0, stream>>>(x1h, x1l, bt_hi, bt_lo, (float*)qkvb);
    // 10: dense self-attention -> ctx planes
    attn_dense_kernel<<<dim3(8, 64), dim3(512), 0, stream>>>(qkvb, c2h, c2l);
    // 11: Wo-S accumulate xg1
    wo_s_kernel<<<dim3(64, 4), B128, 0, stream>>>(c2h, c2l, bt_hi, bt_lo, xg1);
    // 12: LN3 (no relu) -> A3 planes
    ln_pl_kernel<0, 0><<<LN, T64, 0, stream>>>(xg1, ln_g, ln_b, a3h, a3l, nullptr);
    // 13: aggregation GEMM (plane A; tr tiles y<8, in-register gate y=8)
    aggr_gemm_kernel<<<dim3(128, 9), T64, 0, stream>>>(a3h, a3l, bt_hi, bt_lo,
        tr_b, gate_b1, gate_w2, gate_b2, tmp0, gv);
    // 14: weighted sum + head (last-block finisher)
    wsum_head_kernel<<<dim3(64), B256, 0, stream>>>(gv, tmp0, partial, denp,
        mpart, head_w, head_b, (float*)d_out, ticket);
}

// Round 14
// 192.009 us; speedup vs baseline: 1.0478x; 1.0478x over previous
//
#include <hip/hip_runtime.h>
#include <hip/hip_bf16.h>
#include <cmath>
#include <cstdint>

typedef unsigned int u32;
typedef unsigned char u8;
typedef unsigned short ushort;
typedef __attribute__((ext_vector_type(8))) short short8;
typedef __attribute__((ext_vector_type(4))) float f32x4;
typedef __attribute__((ext_vector_type(16))) float f32x16;
typedef __attribute__((ext_vector_type(4))) unsigned short us4;

#define Gn 2048
#define Hd 256
#define CSTRIDE 192

static __device__ __forceinline__ ushort f2bf(float x) {
    __hip_bfloat16 b = __float2bfloat16(x);
    return *reinterpret_cast<ushort*>(&b);
}
static __device__ __forceinline__ float bf2f(ushort u) {
    return __uint_as_float(((u32)u) << 16);
}
// bf16x3 split: hi = truncate, lo = rne(x - hi). Same math everywhere.
static __device__ __forceinline__ void split2(float x, ushort& h, ushort& lo) {
    const u32 bi = __float_as_uint(x);
    h = (ushort)(bi >> 16);
    lo = f2bf(x - __uint_as_float(bi & 0xffff0000u));
}

// ===========================================================================
// Weight arenas are FRAGMENT-MAJOR: a wave's B-fragment (16 cols x 32 k) is
// one contiguous 1KB burst (lane l reads [base + l*8 .. +8)).
// R14 = R12 skeleton (11 dispatches) + zero-launch-cost planes: attention
// epilogues emit ctx hi/lo planes so wo_m/wo_s/qkvs skip all A-split VALU.
// ===========================================================================

// ===========================================================================
// fp32-A GEMM body (R12): in-loop split; LNF = LN(+LNRELU) fused on A rows;
// WRA: (by==0 && bz==0) blocks write normalized A rows to Aout.
// OUTMODE 1 = QKV bf16 epilogue (Q pre-scaled 1/sqrt(32)*log2e).
// QKVMODE 1 (M): V row-layout; QKVMODE 2 (S): V transposed.
// ===========================================================================
template <int BETA, int OUTMODE, int QKVMODE, int KT, int LNF, int LNRELU, int WRA>
static __device__ __forceinline__ void gemm_body(
    const int bx, const int by, const int bz,
    const float* __restrict__ A, int lda,
    const ushort* __restrict__ bt_hi, const ushort* __restrict__ bt_lo,
    int slot0, int slot2, const float* __restrict__ bias,
    const float* __restrict__ lng, const float* __restrict__ lnb,
    float* __restrict__ C, int N, float* __restrict__ Aout)
{
    const int tid = threadIdx.x;
    const int wv = tid >> 6, l = tid & 63;
    const int lr = l & 15, lg = l >> 4;
    const int row = bx * 32 + wv * 16 + lr;
    const int col0 = by * 64;
    int slot = slot0, zq = 0, buf = 0;
    if (QKVMODE == 1) { slot = slot0 + bz + bz / 3; zq = bz % 3; buf = bz / 3; }
    else if (QKVMODE == 2) { slot = slot0 + bz; zq = bz; }
    const ushort* bhb = bt_hi + (long)slot * 65536;
    const ushort* blb = bt_lo + (long)slot * 65536;
    const float* arow = A + (long)row * lda;

    float mean = 0.f, rs = 0.f;
    if (LNF) {
        float s = 0.f, s2 = 0.f;
        #pragma unroll
        for (int ks = 0; ks < 8; ++ks) {
            const float4 a0 = *(const float4*)&arow[ks * 32 + lg * 8];
            const float4 a1 = *(const float4*)&arow[ks * 32 + lg * 8 + 4];
            s  += (a0.x + a0.y) + (a0.z + a0.w) + (a1.x + a1.y) + (a1.z + a1.w);
            s2 += a0.x * a0.x + a0.y * a0.y + a0.z * a0.z + a0.w * a0.w +
                  a1.x * a1.x + a1.y * a1.y + a1.z * a1.z + a1.w * a1.w;
        }
        s += __shfl_xor(s, 16);  s += __shfl_xor(s, 32);
        s2 += __shfl_xor(s2, 16); s2 += __shfl_xor(s2, 32);
        mean = s * (1.f / 256.f);
        rs = rsqrtf(s2 * (1.f / 256.f) - mean * mean + 1e-5f);
    }

    const f32x4 z4 = {0.f, 0.f, 0.f, 0.f};
    f32x4 acc[4] = {z4, z4, z4, z4};

    #pragma unroll
    for (int ks = 0; ks < KT / 32; ++ks) {
        const int k0 = ks * 32;
        float av[8];
        *(float4*)&av[0] = *(const float4*)&arow[k0 + lg * 8];
        *(float4*)&av[4] = *(const float4*)&arow[k0 + lg * 8 + 4];
        if (LNF) {
            float gvv[8], bvv[8];
            *(float4*)&gvv[0] = *(const float4*)&lng[k0 + lg * 8];
            *(float4*)&gvv[4] = *(const float4*)&lng[k0 + lg * 8 + 4];
            *(float4*)&bvv[0] = *(const float4*)&lnb[k0 + lg * 8];
            *(float4*)&bvv[4] = *(const float4*)&lnb[k0 + lg * 8 + 4];
            #pragma unroll
            for (int j = 0; j < 8; ++j) {
                float v = (av[j] - mean) * rs * gvv[j] + bvv[j];
                if (LNRELU) v = fmaxf(v, 0.f);
                av[j] = v;
            }
            if (WRA && by == 0 && bz == 0) {
                *(float4*)&Aout[(long)row * 256 + k0 + lg * 8] = *(float4*)&av[0];
                *(float4*)&Aout[(long)row * 256 + k0 + lg * 8 + 4] = *(float4*)&av[4];
            }
        }
        short8 ahi, alo;
        #pragma unroll
        for (int j = 0; j < 8; ++j) {
            ushort hh, ll;
            split2(av[j], hh, ll);
            ahi[j] = (short)hh; alo[j] = (short)ll;
        }
        #pragma unroll
        for (int f = 0; f < 4; ++f) {
            const long bo = (long)(((by * 4 + f) * 8 + ks) << 9) + (l << 3);
            const short8 bhi = *(const short8*)&bhb[bo];
            const short8 blo = *(const short8*)&blb[bo];
            acc[f] = __builtin_amdgcn_mfma_f32_16x16x32_bf16(ahi, bhi, acc[f], 0, 0, 0);
            acc[f] = __builtin_amdgcn_mfma_f32_16x16x32_bf16(alo, bhi, acc[f], 0, 0, 0);
            acc[f] = __builtin_amdgcn_mfma_f32_16x16x32_bf16(ahi, blo, acc[f], 0, 0, 0);
        }
    }

    const float QS = 0.17677669529663687f * 1.4426950408889634f;

    #pragma unroll
    for (int f = 0; f < 4; ++f) {
        const int col = col0 + f * 16 + lr;
        const float bv = bias ? bias[col] : 0.f;
        #pragma unroll
        for (int r = 0; r < 4; ++r) {
            const int rr = bx * 32 + wv * 16 + lg * 4 + r;
            float v = acc[f][r] + bv;
            if (OUTMODE == 1) {
                if (zq == 0) v *= QS;
                ushort* ob = (ushort*)C + (long)buf * 1572864;
                const int h = col >> 5, d = col & 31;
                if (QKVMODE == 1 || zq < 2)
                    ob[zq * 524288 + ((h * 2048 + rr) << 5) + d] = f2bf(v);
                else
                    ob[1048576 + ((h * 32 + d) << 11) + rr] = f2bf(v);
            } else {
                if (BETA) v += C[(long)rr * N + col];
                C[(long)rr * N + col] = v;
            }
        }
    }
}

// ===========================================================================
// Plane-A GEMM body (A pre-split hi/lo): no split VALU, half A bytes.
// WPL: epilogue also writes result hi/lo planes. KT=512: ks>=8 -> slot2.
// ===========================================================================
template <int BETA, int OUTMODE, int QKVMODE, int KT, int WPL>
static __device__ __forceinline__ void gemm_pl(
    const int bx, const int by, const int bz,
    const ushort* __restrict__ ah, const ushort* __restrict__ al, int lda,
    const ushort* __restrict__ bt_hi, const ushort* __restrict__ bt_lo,
    int slot0, int slot2, const float* __restrict__ bias,
    float* __restrict__ C, int N,
    ushort* __restrict__ xh, ushort* __restrict__ xl)
{
    const int tid = threadIdx.x;
    const int wv = tid >> 6, l = tid & 63;
    const int lr = l & 15, lg = l >> 4;
    const int row = bx * 32 + wv * 16 + lr;
    const int col0 = by * 64;
    int slot = slot0, zq = 0;
    if (QKVMODE == 2) { slot = slot0 + bz; zq = bz; }
    const ushort* bhb = bt_hi + (long)slot * 65536;
    const ushort* blb = bt_lo + (long)slot * 65536;
    const ushort* arh = ah + (long)row * lda;
    const ushort* arl = al + (long)row * lda;

    const f32x4 z4 = {0.f, 0.f, 0.f, 0.f};
    f32x4 acc[4] = {z4, z4, z4, z4};

    #pragma unroll
    for (int ks = 0; ks < KT / 32; ++ks) {
        const int k0 = ks * 32;
        const ushort* bh; const ushort* bl; int kbi = ks;
        if (KT == 512 && k0 >= 256) {
            bh = bt_hi + (long)slot2 * 65536;
            bl = bt_lo + (long)slot2 * 65536;
            kbi = ks - 8;
        } else { bh = bhb; bl = blb; }
        const short8 ahi = *(const short8*)&arh[k0 + lg * 8];
        const short8 alo = *(const short8*)&arl[k0 + lg * 8];
        #pragma unroll
        for (int f = 0; f < 4; ++f) {
            const long bo = (long)(((by * 4 + f) * 8 + kbi) << 9) + (l << 3);
            const short8 bhi = *(const short8*)&bh[bo];
            const short8 blo = *(const short8*)&bl[bo];
            acc[f] = __builtin_amdgcn_mfma_f32_16x16x32_bf16(ahi, bhi, acc[f], 0, 0, 0);
            acc[f] = __builtin_amdgcn_mfma_f32_16x16x32_bf16(alo, bhi, acc[f], 0, 0, 0);
            acc[f] = __builtin_amdgcn_mfma_f32_16x16x32_bf16(ahi, blo, acc[f], 0, 0, 0);
        }
    }

    const float QS = 0.17677669529663687f * 1.4426950408889634f;

    #pragma unroll
    for (int f = 0; f < 4; ++f) {
        const int col = col0 + f * 16 + lr;
        const float bv = bias ? bias[col] : 0.f;
        #pragma unroll
        for (int r = 0; r < 4; ++r) {
            const int rr = bx * 32 + wv * 16 + lg * 4 + r;
            float v = acc[f][r] + bv;
            if (OUTMODE == 1) {
                if (zq == 0) v *= QS;
                ushort* ob = (ushort*)C;
                const int h = col >> 5, d = col & 31;
                if (zq < 2) ob[zq * 524288 + ((h * 2048 + rr) << 5) + d] = f2bf(v);
                else        ob[1048576 + ((h * 32 + d) << 11) + rr] = f2bf(v);
            } else {
                if (BETA) v += C[(long)rr * N + col];
                C[(long)rr * N + col] = v;
                if (WPL) {
                    ushort hh, ll;
                    split2(v, hh, ll);
                    xh[(long)rr * 256 + col] = hh;
                    xl[(long)rr * 256 + col] = ll;
                }
            }
        }
    }
}

// ===========================================================================
// Merged A (256 thr, grid 192): blocks 0-63 mask-dtype detect; blocks 64-191
// weight pre-split (fragment-major). Block 0 zeroes the wsum ticket.
// ===========================================================================
__global__ __launch_bounds__(256) void mergedA_kernel(
    const u8* __restrict__ adj, int* __restrict__ det0, int* __restrict__ det1,
    const float* __restrict__ pre_w1, const float* __restrict__ pre_w2,
    const float* __restrict__ wm, const float* __restrict__ wsw,
    const float* __restrict__ gate_w1, const float* __restrict__ tr_w,
    ushort* __restrict__ bt_hi, ushort* __restrict__ bt_lo,
    u32* __restrict__ ticket)
{
    __shared__ float T[32][257];
    __shared__ int sd0[4], sd1[4];
    const int tid = threadIdx.x;
    if (blockIdx.x == 0 && tid == 0) *ticket = 0;
    if (blockIdx.x < 64) {
        const int idx = blockIdx.x * 256 + tid;
        const uint4 w = ((const uint4*)adj)[idx];
        int c0 = ((w.x & 0xffu) ? 1 : 0) + ((w.y & 0xffu) ? 1 : 0) +
                 ((w.z & 0xffu) ? 1 : 0) + ((w.w & 0xffu) ? 1 : 0);
        int c1 = ((w.x & 0xffffff00u) ? 1 : 0) + ((w.y & 0xffffff00u) ? 1 : 0) +
                 ((w.z & 0xffffff00u) ? 1 : 0) + ((w.w & 0xffffff00u) ? 1 : 0);
        #pragma unroll
        for (int o = 1; o < 64; o <<= 1) { c0 += __shfl_xor(c0, o); c1 += __shfl_xor(c1, o); }
        if ((tid & 63) == 0) { sd0[tid >> 6] = c0; sd1[tid >> 6] = c1; }
        __syncthreads();
        if (tid == 0) {
            det0[blockIdx.x] = sd0[0] + sd0[1] + sd0[2] + sd0[3];
            det1[blockIdx.x] = sd1[0] + sd1[1] + sd1[2] + sd1[3];
        }
        return;
    }
    const int b2 = blockIdx.x - 64;
    const int slot = b2 >> 3;
    const int kb = b2 & 7;
    const int k0 = kb * 32;
    const float* src; int ncols = 256;
    if (slot == 0) src = pre_w1;
    else if (slot == 1) src = pre_w2;
    else if (slot < 6) src = wm + (long)(slot - 2) * 65536;
    else if (slot < 10) src = wm + (long)(4 + slot - 6) * 65536;
    else if (slot < 14) src = wsw + (long)(slot - 10) * 65536;
    else if (slot == 14) { src = gate_w1; ncols = 128; }
    else src = tr_w;

    const int lsh = (ncols == 256) ? 6 : 5;
    const int tot = 32 << lsh;
    for (int i = tid; i < tot; i += 256) {
        const int kk = i >> lsh, c4 = (i & ((1 << lsh) - 1)) << 2;
        const float4 v = *(const float4*)&src[(long)(k0 + kk) * ncols + c4];
        T[kk][c4 + 0] = v.x; T[kk][c4 + 1] = v.y;
        T[kk][c4 + 2] = v.z; T[kk][c4 + 3] = v.w;
    }
    __syncthreads();
    if (tid < ncols) {
        ushort hb[32], lb[32];
        #pragma unroll
        for (int kk = 0; kk < 32; ++kk) split2(T[kk][tid], hb[kk], lb[kk]);
        const int cb = tid >> 4, lr = tid & 15;
        const long base = (long)slot * 65536 + ((cb * 8 + kb) << 9);
        ushort* oh = bt_hi + base;
        ushort* ol = bt_lo + base;
        #pragma unroll
        for (int lg2 = 0; lg2 < 4; ++lg2) {
            const int off = (lg2 * 16 + lr) << 3;
            *(uint4*)&oh[off] = *(const uint4*)&hb[lg2 * 8];
            *(uint4*)&ol[off] = *(const uint4*)&lb[lg2 * 8];
        }
    }
}

// ===========================================================================
// Merged B (128 thr, grid 2304): blocks 0-2047 pack masks + CSR for their 2
// rows; blocks 2048-2303 preGEMM1 (tmp0 = gene_emb @ pre_w1 + b1).
// ===========================================================================
__global__ __launch_bounds__(128) void mergedB_kernel(
    const u8* __restrict__ src0, const u8* __restrict__ src1,
    const int* __restrict__ det0, const int* __restrict__ det1,
    u32* __restrict__ bits, int* __restrict__ deg, int* __restrict__ colidx,
    const float* __restrict__ gene_emb,
    const ushort* __restrict__ bt_hi, const ushort* __restrict__ bt_lo,
    const float* __restrict__ pre_b1, float* __restrict__ tmp0)
{
    __shared__ u32 sw[128];
    const int tid = threadIdx.x;
    if (blockIdx.x < 2048) {
        const int lane = tid & 63;
        int c0 = det0[lane], c1 = det1[lane];
        #pragma unroll
        for (int o = 1; o < 64; o <<= 1) { c0 += __shfl_xor(c0, o); c1 += __shfl_xor(c1, o); }
        const int f = (c0 > 0) ? ((c1 > 0) ? 1 : 0) : 2;
        const int W = blockIdx.x * 128 + tid;
        const int z = W >> 17;
        const int rem = W & 131071;
        const int row = rem >> 6, w = rem & 63;
        const u8* src = z ? src1 : src0;
        u32 v = 0;
        if (f == 1) {
            const uint4* p = (const uint4*)(src + (long)row * 2048 + w * 32);
            const uint4 q0 = p[0], q1 = p[1];
            const u32 ws8[8] = {q0.x, q0.y, q0.z, q0.w, q1.x, q1.y, q1.z, q1.w};
            #pragma unroll
            for (int j = 0; j < 8; ++j) {
                const u32 x = ws8[j];
                const u32 m = (((x & 0x7f7f7f7fu) + 0x7f7f7f7fu) | x) & 0x80808080u;
                const u32 b4 = ((m >> 7) & 1u) | ((m >> 14) & 2u) |
                               ((m >> 21) & 4u) | ((m >> 28) & 8u);
                v |= b4 << (j * 4);
            }
        } else if (f == 0) {
            const uint4* p = (const uint4*)((const int*)src + (long)row * 2048 + w * 32);
            #pragma unroll
            for (int j = 0; j < 8; ++j) {
                const uint4 q = p[j];
                v |= (q.x ? 1u : 0u) << (j * 4 + 0);
                v |= (q.y ? 1u : 0u) << (j * 4 + 1);
                v |= (q.z ? 1u : 0u) << (j * 4 + 2);
                v |= (q.w ? 1u : 0u) << (j * 4 + 3);
            }
        } else {
            const uint4* p = (const uint4*)((const float*)src + (long)row * 2048 + w * 32);
            #pragma unroll
            for (int j = 0; j < 8; ++j) {
                const uint4 q = p[j];
                v |= ((q.x & 0x7fffffffu) ? 1u : 0u) << (j * 4 + 0);
                v |= ((q.y & 0x7fffffffu) ? 1u : 0u) << (j * 4 + 1);
                v |= ((q.z & 0x7fffffffu) ? 1u : 0u) << (j * 4 + 2);
                v |= ((q.w & 0x7fffffffu) ? 1u : 0u) << (j * 4 + 3);
            }
        }
        bits[(long)z * 131072 + rem] = v;
        sw[tid] = v;
        __syncthreads();
        if (tid < 2) {
            const int rem0 = (blockIdx.x * 128) & 131071;
            const int r = (rem0 >> 6) + tid;
            int* ci = colidx + ((long)z * 2048 + r) * CSTRIDE;
            int d = 0;
            #pragma unroll 4
            for (int ww = 0; ww < 64; ++ww) {
                u32 x = sw[tid * 64 + ww];
                while (x) {
                    const int j = __ffs(x) - 1;
                    if (d < CSTRIDE) ci[d] = ww * 32 + j;
                    ++d;
                    x &= x - 1;
                }
            }
            deg[z * 2048 + r] = d < CSTRIDE ? d : CSTRIDE;
        }
        return;
    }
    const int b2 = blockIdx.x - 2048;
    gemm_body<0, 0, 0, 256, 0, 0, 0>(b2 >> 2, b2 & 3, 0, gene_emb, 256,
                                     bt_hi, bt_lo, 0, 0, pre_b1,
                                     nullptr, nullptr, tmp0, 256, nullptr);
}

// ===========================================================================
// Merged C (128 thr, grid 256): preGEMM2 with LN1+relu fused on A.
// ===========================================================================
__global__ __launch_bounds__(128) void mergedC_kernel(
    const float* __restrict__ tmp0,
    const ushort* __restrict__ bt_hi, const ushort* __restrict__ bt_lo,
    const float* __restrict__ pre_b2, const float* __restrict__ pre_ln_g,
    const float* __restrict__ pre_ln_b, float* __restrict__ tmp1)
{
    const int b2 = blockIdx.x;
    gemm_body<0, 0, 0, 256, 1, 1, 0>(b2 >> 2, b2 & 3, 0, tmp0, 256,
                                     bt_hi, bt_lo, 1, 0, pre_b2,
                                     pre_ln_g, pre_ln_b, tmp1, 256, nullptr);
}

// GEMM wrappers ------------------------------------------------------------
__global__ __launch_bounds__(128) void qkvm_kernel(    // LN2+relu fused; writes xg1
    const float* __restrict__ tmp1,
    const ushort* __restrict__ bt_hi, const ushort* __restrict__ bt_lo,
    const float* __restrict__ pre_ln_g, const float* __restrict__ pre_ln_b,
    float* __restrict__ qkvb, float* __restrict__ xg1)
{
    gemm_body<0, 1, 1, 256, 1, 1, 1>(blockIdx.x, blockIdx.y, blockIdx.z,
                                     tmp1, 256, bt_hi, bt_lo, 2, 0, nullptr,
                                     pre_ln_g, pre_ln_b, qkvb, 256, xg1);
}
__global__ __launch_bounds__(128) void wo_m_kernel(    // plane A; emits xg1 planes
    const ushort* __restrict__ c2h, const ushort* __restrict__ c2l,
    const ushort* __restrict__ bt_hi, const ushort* __restrict__ bt_lo,
    float* __restrict__ xg1, ushort* __restrict__ x1h, ushort* __restrict__ x1l)
{
    gemm_pl<1, 0, 0, 512, 1>(blockIdx.x, blockIdx.y, 0, c2h, c2l, 512,
                             bt_hi, bt_lo, 5, 9, nullptr, xg1, 256, x1h, x1l);
}
__global__ __launch_bounds__(128) void qkvs_kernel(    // plane A
    const ushort* __restrict__ x1h, const ushort* __restrict__ x1l,
    const ushort* __restrict__ bt_hi, const ushort* __restrict__ bt_lo,
    float* __restrict__ qkvb)
{
    gemm_pl<0, 1, 2, 256, 0>(blockIdx.x, blockIdx.y, blockIdx.z, x1h, x1l, 256,
                             bt_hi, bt_lo, 10, 0, nullptr, qkvb, 256, nullptr, nullptr);
}
__global__ __launch_bounds__(128) void wo_s_kernel(    // plane A
    const ushort* __restrict__ c2h, const ushort* __restrict__ c2l,
    const ushort* __restrict__ bt_hi, const ushort* __restrict__ bt_lo,
    float* __restrict__ xg1)
{
    gemm_pl<1, 0, 0, 256, 0>(blockIdx.x, blockIdx.y, 0, c2h, c2l, 512,
                             bt_hi, bt_lo, 13, 0, nullptr, xg1, 256, nullptr, nullptr);
}

// ===========================================================================
// Sparse masked attention (M block), exp2 domain. One wave per (row, graph).
// Writes ctx hi/lo planes (stride 512; z selects column half).
// ===========================================================================
__global__ __launch_bounds__(64) void attn_sparse_kernel(
    const ushort* __restrict__ qkvb, const int* __restrict__ deg,
    const int* __restrict__ colidx, ushort* __restrict__ ch, ushort* __restrict__ cl)
{
    const int r = blockIdx.x, z = blockIdx.y;
    const ushort* qb = qkvb + (long)z * 1572864;
    const ushort* kb = qb + 524288;
    const ushort* vr = qb + 1048576;
    const int l = threadIdx.x;
    const int h = l >> 3, dg = l & 7;
    const long ooff = (long)r * 512 + z * 256 + h * 32 + dg * 4;
    const int n = deg[z * 2048 + r];
    float o[4];
    if (n == 0) {
        float a0 = 0.f, a1 = 0.f, a2 = 0.f, a3 = 0.f;
        for (int k = 0; k < 2048; ++k) {
            const us4 vv = *(const us4*)&vr[((h * 2048 + k) << 5) + dg * 4];
            a0 += bf2f(vv[0]); a1 += bf2f(vv[1]); a2 += bf2f(vv[2]); a3 += bf2f(vv[3]);
        }
        const float inv = 1.f / 2048.f;
        o[0] = a0 * inv; o[1] = a1 * inv; o[2] = a2 * inv; o[3] = a3 * inv;
    } else {
        float q0, q1, q2, q3;
        {
            const us4 qv = *(const us4*)&qb[((h * 2048 + r) << 5) + dg * 4];
            q0 = bf2f(qv[0]); q1 = bf2f(qv[1]); q2 = bf2f(qv[2]); q3 = bf2f(qv[3]);
        }
        const int* ci = colidx + ((long)z * 2048 + r) * CSTRIDE;
        float m = -INFINITY, lsum = 0.f;
        float a0 = 0.f, a1 = 0.f, a2 = 0.f, a3 = 0.f;
        int kn = ci[0];
        us4 kv = *(const us4*)&kb[((h * 2048 + kn) << 5) + dg * 4];
        us4 vv = *(const us4*)&vr[((h * 2048 + kn) << 5) + dg * 4];
        for (int e = 0; e < n; ++e) {
            const us4 kc = kv, vc = vv;
            if (e + 1 < n) {
                kn = ci[e + 1];
                kv = *(const us4*)&kb[((h * 2048 + kn) << 5) + dg * 4];
                vv = *(const us4*)&vr[((h * 2048 + kn) << 5) + dg * 4];
            }
            float s = q0 * bf2f(kc[0]) + q1 * bf2f(kc[1]) +
                      q2 * bf2f(kc[2]) + q3 * bf2f(kc[3]);
            s += __shfl_xor(s, 1); s += __shfl_xor(s, 2); s += __shfl_xor(s, 4);
            const float mn = fmaxf(m, s);
            const float fac = __builtin_amdgcn_exp2f(m - mn);
            const float p = __builtin_amdgcn_exp2f(s - mn);
            lsum = lsum * fac + p;
            a0 = a0 * fac + p * bf2f(vc[0]);
            a1 = a1 * fac + p * bf2f(vc[1]);
            a2 = a2 * fac + p * bf2f(vc[2]);
            a3 = a3 * fac + p * bf2f(vc[3]);
            m = mn;
        }
        const float inv = 1.f / lsum;
        o[0] = a0 * inv; o[1] = a1 * inv; o[2] = a2 * inv; o[3] = a3 * inv;
    }
    us4 h4, l4;
    #pragma unroll
    for (int j = 0; j < 4; ++j) { ushort hh, ll; split2(o[j], hh, ll); h4[j] = hh; l4[j] = ll; }
    *(us4*)&ch[ooff] = h4;
    *(us4*)&cl[ooff] = l4;
}

// ===========================================================================
// Dense attention (S block): 32x32x16 swapped MFMA, in-register P, exp2,
// k-split x8 (512 thr), parallel 8-way merge, plane output.
// ===========================================================================
__global__ __launch_bounds__(512) void attn_dense_kernel(
    const ushort* __restrict__ qkvb, ushort* __restrict__ ch, ushort* __restrict__ cl)
{
    const ushort* qb = qkvb;
    const ushort* kb = qb + 524288;
    const ushort* vt = qb + 1048576;
    const int h = blockIdx.x, qt = blockIdx.y;
    const int wv = threadIdx.x >> 6;
    const int l = threadIdx.x & 63;
    const int lq = l & 31;
    const int hi = l >> 5;
    const int qglob = qt * 32 + lq;

    __shared__ float Mm[8][32], Ml[8][32];
    __shared__ float Macc[8][64][17];
    __shared__ float ctile[32][33];

    const int qoff = ((h * 2048 + qglob) << 5) + hi * 8;
    const short8 qf0 = *(const short8*)&qb[qoff];
    const short8 qf1 = *(const short8*)&qb[qoff + 16];

    float m = -INFINITY, lsum = 0.f;
    f32x16 acc, zz16;
    #pragma unroll
    for (int i = 0; i < 16; ++i) { acc[i] = 0.f; zz16[i] = 0.f; }

    const int kt0 = wv * 256;
    #pragma unroll 2
    for (int it = 0; it < 8; ++it) {
        const int kbase = kt0 + it * 32;
        const int koff = ((h * 2048 + kbase + lq) << 5) + hi * 8;
        const short8 kf0 = *(const short8*)&kb[koff];
        const short8 kf1 = *(const short8*)&kb[koff + 16];
        f32x16 s = __builtin_amdgcn_mfma_f32_32x32x16_bf16(kf0, qf0, zz16, 0, 0, 0);
        s = __builtin_amdgcn_mfma_f32_32x32x16_bf16(kf1, qf1, s, 0, 0, 0);
        float sc[16];
        #pragma unroll
        for (int i = 0; i < 16; ++i) sc[i] = s[i];
        float t[8];
        #pragma unroll
        for (int i = 0; i < 8; ++i) t[i] = fmaxf(sc[i], sc[i + 8]);
        #pragma unroll
        for (int i = 0; i < 4; ++i) t[i] = fmaxf(t[i], t[i + 4]);
        float mt = fmaxf(fmaxf(t[0], t[1]), fmaxf(t[2], t[3]));
        mt = fmaxf(mt, __shfl_xor(mt, 32));
        const float mn = fmaxf(m, mt);
        if (__ballot(mn != m)) {
            const float fac = __builtin_amdgcn_exp2f(m - mn);
            lsum *= fac;
            #pragma unroll
            for (int i = 0; i < 16; ++i) acc[i] *= fac;
            m = mn;
        }
        #pragma unroll
        for (int i = 0; i < 16; ++i) sc[i] = __builtin_amdgcn_exp2f(sc[i] - m);
        #pragma unroll
        for (int i = 0; i < 8; ++i) t[i] = sc[i] + sc[i + 8];
        #pragma unroll
        for (int i = 0; i < 4; ++i) t[i] = t[i] + t[i + 4];
        float ps = (t[0] + t[1]) + (t[2] + t[3]);
        ps += __shfl_xor(ps, 32);
        lsum += ps;
        u32 pk[8];
        #pragma unroll
        for (int g = 0; g < 4; ++g) {
            asm("v_cvt_pk_bf16_f32 %0, %1, %2"
                : "=v"(pk[2 * g]) : "v"(sc[4 * g + 0]), "v"(sc[4 * g + 1]));
            asm("v_cvt_pk_bf16_f32 %0, %1, %2"
                : "=v"(pk[2 * g + 1]) : "v"(sc[4 * g + 2]), "v"(sc[4 * g + 3]));
        }
        asm volatile("v_permlane32_swap_b32 %0, %1" : "+v"(pk[0]), "+v"(pk[2]));
        asm volatile("v_permlane32_swap_b32 %0, %1" : "+v"(pk[1]), "+v"(pk[3]));
        asm volatile("v_permlane32_swap_b32 %0, %1" : "+v"(pk[4]), "+v"(pk[6]));
        asm volatile("v_permlane32_swap_b32 %0, %1" : "+v"(pk[5]), "+v"(pk[7]));
        short8 pB0, pB1;
        ((u32*)&pB0)[0] = pk[0]; ((u32*)&pB0)[1] = pk[1];
        ((u32*)&pB0)[2] = pk[2]; ((u32*)&pB0)[3] = pk[3];
        ((u32*)&pB1)[0] = pk[4]; ((u32*)&pB1)[1] = pk[5];
        ((u32*)&pB1)[2] = pk[6]; ((u32*)&pB1)[3] = pk[7];
        const int voff = ((h * 32 + lq) << 11) + kbase + hi * 8;
        const short8 vf0 = *(const short8*)&vt[voff];
        const short8 vf1 = *(const short8*)&vt[voff + 16];
        acc = __builtin_amdgcn_mfma_f32_32x32x16_bf16(vf0, pB0, acc, 0, 0, 0);
        acc = __builtin_amdgcn_mfma_f32_32x32x16_bf16(vf1, pB1, acc, 0, 0, 0);
    }

    if (l < 32) { Mm[wv][l] = m; Ml[wv][l] = lsum; }
    #pragma unroll
    for (int i = 0; i < 16; ++i) Macc[wv][l][i] = acc[i];
    __syncthreads();
    {
        const int t = threadIdx.x;
        const int q = t & 31, j = t >> 5;
        float M = Mm[0][q];
        #pragma unroll
        for (int w = 1; w < 8; ++w) M = fmaxf(M, Mm[w][q]);
        float fw[8], den = 0.f;
        #pragma unroll
        for (int w = 0; w < 8; ++w) {
            fw[w] = __builtin_amdgcn_exp2f(Mm[w][q] - M);
            den += Ml[w][q] * fw[w];
        }
        const float inv = 1.f / den;
        #pragma unroll
        for (int half = 0; half < 2; ++half) {
            const int d = j + 16 * half;
            const int i = (d & 3) | ((d >> 3) << 2);
            const int h2 = (d >> 2) & 1;
            float o = 0.f;
            #pragma unroll
            for (int w = 0; w < 8; ++w) o += Macc[w][h2 * 32 + q][i] * fw[w];
            ctile[d][q] = o * inv;
        }
    }
    __syncthreads();
    if (threadIdx.x < 256) {
        const int t = threadIdx.x;
        const int q = t >> 3, d0 = (t & 7) << 2;
        us4 h4, l4;
        #pragma unroll
        for (int j = 0; j < 4; ++j) {
            ushort hh, ll;
            split2(ctile[d0 + j][q], hh, ll);
            h4[j] = hh; l4[j] = ll;
        }
        const long ooff = (long)(qt * 32 + q) * 512 + h * 32 + d0;
        *(us4*)&ch[ooff] = h4;
        *(us4*)&cl[ooff] = l4;
    }
}

// ===========================================================================
// Aggregation GEMM with LN3 fused on A (=xg1 fp32): y<8 -> t tile;
// y==8 -> gate fully in-register.
// ===========================================================================
__global__ __launch_bounds__(64) void aggr_gemm_kernel(
    const float* __restrict__ xg1,
    const ushort* __restrict__ bt_hi, const ushort* __restrict__ bt_lo,
    const float* __restrict__ ln_g, const float* __restrict__ ln_b,
    const float* __restrict__ tr_b, const float* __restrict__ g_b1,
    const float* __restrict__ g_w2, const float* __restrict__ g_b2,
    float* __restrict__ t_out, float* __restrict__ gv)
{
    const int l = threadIdx.x;
    const int lr = l & 15, lg = l >> 4;
    const int row0 = blockIdx.x * 16;
    const int gate = (blockIdx.y == 8);
    const int slot = gate ? 14 : 15;
    const int col0 = gate ? 0 : blockIdx.y * 32;
    const int NF = gate ? 8 : 2;
    const ushort* bh0 = bt_hi + (long)slot * 65536;
    const ushort* bl0 = bt_lo + (long)slot * 65536;
    const float* arow = xg1 + (long)(row0 + lr) * 256;

    float s = 0.f, s2 = 0.f;
    #pragma unroll
    for (int ks = 0; ks < 8; ++ks) {
        const float4 a0 = *(const float4*)&arow[ks * 32 + lg * 8];
        const float4 a1 = *(const float4*)&arow[ks * 32 + lg * 8 + 4];
        s  += (a0.x + a0.y) + (a0.z + a0.w) + (a1.x + a1.y) + (a1.z + a1.w);
        s2 += a0.x * a0.x + a0.y * a0.y + a0.z * a0.z + a0.w * a0.w +
              a1.x * a1.x + a1.y * a1.y + a1.z * a1.z + a1.w * a1.w;
    }
    s += __shfl_xor(s, 16);  s += __shfl_xor(s, 32);
    s2 += __shfl_xor(s2, 16); s2 += __shfl_xor(s2, 32);
    const float mean = s * (1.f / 256.f);
    const float rs = rsqrtf(s2 * (1.f / 256.f) - mean * mean + 1e-5f);

    const f32x4 z4 = {0.f, 0.f, 0.f, 0.f};
    f32x4 acc[8] = {z4, z4, z4, z4, z4, z4, z4, z4};

    #pragma unroll
    for (int ks = 0; ks < 8; ++ks) {
        const int k0 = ks * 32;
        float av[8], gvv[8], bvv[8];
        *(float4*)&av[0] = *(const float4*)&arow[k0 + lg * 8];
        *(float4*)&av[4] = *(const float4*)&arow[k0 + lg * 8 + 4];
        *(float4*)&gvv[0] = *(const float4*)&ln_g[k0 + lg * 8];
        *(float4*)&gvv[4] = *(const float4*)&ln_g[k0 + lg * 8 + 4];
        *(float4*)&bvv[0] = *(const float4*)&ln_b[k0 + lg * 8];
        *(float4*)&bvv[4] = *(const float4*)&ln_b[k0 + lg * 8 + 4];
        short8 ahi, alo;
        #pragma unroll
        for (int j = 0; j < 8; ++j) {
            const float vn = (av[j] - mean) * rs * gvv[j] + bvv[j];
            ushort hh, ll;
            split2(vn, hh, ll);
            ahi[j] = (short)hh; alo[j] = (short)ll;
        }
        for (int f = 0; f < NF; ++f) {
            const int cb = gate ? f : ((int)blockIdx.y * 2 + f);
            const long bo = (long)((cb * 8 + ks) << 9) + (l << 3);
            const short8 bhi = *(const short8*)&bh0[bo];
            const short8 blo = *(const short8*)&bl0[bo];
            acc[f] = __builtin_amdgcn_mfma_f32_16x16x32_bf16(ahi, bhi, acc[f], 0, 0, 0);
            acc[f] = __builtin_amdgcn_mfma_f32_16x16x32_bf16(alo, bhi, acc[f], 0, 0, 0);
            acc[f] = __builtin_amdgcn_mfma_f32_16x16x32_bf16(ahi, blo, acc[f], 0, 0, 0);
        }
    }

    if (!gate) {
        #pragma unroll
        for (int f = 0; f < 2; ++f) {
            const int col = col0 + f * 16 + lr;
            const float bv = tr_b[col];
            #pragma unroll
            for (int r = 0; r < 4; ++r) {
                const int rr = row0 + lg * 4 + r;
                t_out[(long)rr * 256 + col] = fmaxf(acc[f][r] + bv, 0.f);
            }
        }
    } else {
        float b1v[8], w2v[8];
        #pragma unroll
        for (int f = 0; f < 8; ++f) {
            b1v[f] = g_b1[f * 16 + lr];
            w2v[f] = g_w2[f * 16 + lr];
        }
        const float b2 = g_b2[0];
        #pragma unroll
        for (int r = 0; r < 4; ++r) {
            float t = 0.f;
            #pragma unroll
            for (int f = 0; f < 8; ++f)
                t += fmaxf(acc[f][r] + b1v[f], 0.f) * w2v[f];
            #pragma unroll
            for (int o = 1; o < 16; o <<= 1) t += __shfl_xor(t, o);
            if (lr == 0) gv[row0 + lg * 4 + r] = t + b2;
        }
    }
}

// ===========================================================================
// wsum + head (last-block finisher)
// ===========================================================================
__global__ __launch_bounds__(256) void wsum_head_kernel(
    const float* __restrict__ gv, const float* __restrict__ t,
    float* __restrict__ partial, float* __restrict__ denp, float* __restrict__ mpart,
    const float* __restrict__ hw, const float* __restrict__ hb,
    float* __restrict__ out, u32* __restrict__ ticket)
{
    const float L2E = 1.4426950408889634f;
    const int b = blockIdx.x, tid = threadIdx.x;
    float M = -INFINITY;
    #pragma unroll
    for (int i = 0; i < 32; ++i) M = fmaxf(M, gv[b * 32 + i]);
    float s = 0.f, den = 0.f;
    #pragma unroll 4
    for (int i = 0; i < 32; ++i) {
        const int r = b * 32 + i;
        const float w = __builtin_amdgcn_exp2f((gv[r] - M) * L2E);
        den += w;
        s += w * t[(long)r * 256 + tid];
    }
    partial[b * 256 + tid] = s;
    if (tid == 0) { denp[b] = den; mpart[b] = M; }
    __threadfence();
    __syncthreads();
    __shared__ int lastFlag;
    if (tid == 0) lastFlag = (atomicAdd(ticket, 1u) == 63u) ? 1 : 0;
    __syncthreads();
    if (!lastFlag) return;
    __threadfence();

    __shared__ float fb[64];
    __shared__ float dtot;
    __shared__ float red0[4], red1[4];
    if (tid < 64) {
        const float mb = mpart[tid];
        float Mg = mb;
        #pragma unroll
        for (int o = 1; o < 64; o <<= 1) Mg = fmaxf(Mg, __shfl_xor(Mg, o));
        const float f = __builtin_amdgcn_exp2f((mb - Mg) * L2E);
        fb[tid] = f;
        float dv = f * denp[tid];
        #pragma unroll
        for (int o = 1; o < 64; o <<= 1) dv += __shfl_xor(dv, o);
        if (tid == 0) dtot = dv;
    }
    __syncthreads();
    float p = 0.f;
    #pragma unroll 8
    for (int bb = 0; bb < 64; ++bb) p += fb[bb] * partial[bb * 256 + tid];
    p /= dtot;
    float s0 = p * hw[tid * 2 + 0];
    float s1 = p * hw[tid * 2 + 1];
    #pragma unroll
    for (int o = 1; o < 64; o <<= 1) { s0 += __shfl_xor(s0, o); s1 += __shfl_xor(s1, o); }
    if ((tid & 63) == 0) { red0[tid >> 6] = s0; red1[tid >> 6] = s1; }
    __syncthreads();
    if (tid == 0) {
        out[0] = red0[0] + red0[1] + red0[2] + red0[3] + hb[0];
        out[1] = red1[0] + red1[1] + red1[2] + red1[3] + hb[1];
    }
}

// ---------------------------------------------------------------------------
extern "C" void kernel_launch(void* const* d_in, const int* in_sizes, int n_in,
                              void* d_out, int out_size, void* d_ws, size_t ws_size,
                              hipStream_t stream)
{
    (void)in_sizes; (void)n_in; (void)out_size; (void)ws_size;
    const float* gene_emb = (const float*)d_in[0];
    const float* pre_w1   = (const float*)d_in[3];
    const float* pre_b1   = (const float*)d_in[4];
    const float* pre_w2   = (const float*)d_in[5];
    const float* pre_b2   = (const float*)d_in[6];
    const float* pre_ln_g = (const float*)d_in[7];
    const float* pre_ln_b = (const float*)d_in[8];
    const float* wm       = (const float*)d_in[9];
    const float* wsw      = (const float*)d_in[10];
    const float* ln_g     = (const float*)d_in[11];
    const float* ln_b     = (const float*)d_in[12];
    const float* gate_w1  = (const float*)d_in[13];
    const float* gate_b1  = (const float*)d_in[14];
    const float* gate_w2  = (const float*)d_in[15];
    const float* gate_b2  = (const float*)d_in[16];
    const float* tr_w     = (const float*)d_in[17];
    const float* tr_b     = (const float*)d_in[18];
    const float* head_w   = (const float*)d_in[19];
    const float* head_b   = (const float*)d_in[20];
    const u8* adj_pp      = (const u8*)d_in[21];
    const u8* adj_rr      = (const u8*)d_in[22];
    // d_in[1],[2],[23],[24] dead (reaction/metab branches never reach output)

    const long NHf = (long)Gn * Hd;
    float* tmp0    = (float*)d_ws;          // preG1 out (fp32), later t-matrix
    float* tmp1    = tmp0 + NHf;            // preG2 out (fp32)
    float* xg1     = tmp1 + NHf;            // residual accumulator (fp32)
    float* gv      = xg1 + NHf;             // [2048]
    float* partial = gv + Gn;               // [64][256]
    float* denp    = partial + 64 * 256;
    float* mpart   = denp + 64;
    int* det0      = (int*)(mpart + 64);
    int* det1      = det0 + 64;
    u32* ticket    = (u32*)(det1 + 64);
    int* deg       = (int*)(ticket + 64);
    int* colidx    = deg + 4096;
    u32* bits      = (u32*)(colidx + 2L * 2048 * CSTRIDE);
    ushort* qkvb   = (ushort*)(bits + 262144);     // 2 x 1572864 bf16
    ushort* bt_hi  = qkvb + 2L * 1572864;          // 16 slots x 65536
    ushort* bt_lo  = bt_hi + 16L * 65536;
    ushort* c2h    = bt_lo + 16L * 65536;          // ctx planes [2048][512]
    ushort* c2l    = c2h + 2 * NHf;
    ushort* x1h    = c2l + 2 * NHf;                // xg1 planes [2048][256]
    ushort* x1l    = x1h + NHf;

    dim3 B256(256), B128(128), T64(64);

    // 1: detect || weight pre-split (also zeroes the wsum ticket)
    mergedA_kernel<<<dim3(192), B256, 0, stream>>>(adj_pp, det0, det1,
        pre_w1, pre_w2, wm, wsw, gate_w1, tr_w, bt_hi, bt_lo, ticket);
    // 2: pack masks + CSR || preGEMM1
    mergedB_kernel<<<dim3(2304), B128, 0, stream>>>(adj_pp, adj_rr, det0, det1,
        bits, deg, colidx, gene_emb, bt_hi, bt_lo, pre_b1, tmp0);
    // 3: preGEMM2 (LN1+relu fused)
    mergedC_kernel<<<dim3(256), B128, 0, stream>>>(tmp0, bt_hi, bt_lo,
        pre_b2, pre_ln_g, pre_ln_b, tmp1);
    // 4: QKV-M (LN2+relu fused; writes xg1 fp32)
    qkvm_kernel<<<dim3(64, 4, 6), B128, 0, stream>>>(tmp1, bt_hi, bt_lo,
        pre_ln_g, pre_ln_b, (float*)qkvb, xg1);
    // 5: sparse masked attention -> ctx planes
    attn_sparse_kernel<<<dim3(2048, 2), T64, 0, stream>>>(qkvb, deg, colidx, c2h, c2l);
    // 6: fused dual-Wo (K=512, plane A); accumulates xg1 + emits xg1 planes
    wo_m_kernel<<<dim3(64, 4), B128, 0, stream>>>(c2h, c2l, bt_hi, bt_lo, xg1, x1h, x1l);
    // 7: QKV-S (plane A)
    qkvs_kernel<<<dim3(64, 4, 3), B128, 0, stream>>>(x1h, x1l, bt_hi, bt_lo, (float*)qkvb);
    // 8: dense self-attention -> ctx planes
    attn_dense_kernel<<<dim3(8, 64), dim3(512), 0, stream>>>(qkvb, c2h, c2l);
    // 9: Wo-S (plane A) accumulate xg1
    wo_s_kernel<<<dim3(64, 4), B128, 0, stream>>>(c2h, c2l, bt_hi, bt_lo, xg1);
    // 10: aggregation GEMM (LN3 fused on xg1)
    aggr_gemm_kernel<<<dim3(128, 9), T64, 0, stream>>>(xg1, bt_hi, bt_lo,
        ln_g, ln_b, tr_b, gate_b1, gate_w2, gate_b2, tmp0, gv);
    // 11: weighted sum + head (last-block finisher)
    wsum_head_kernel<<<dim3(64), B256, 0, stream>>>(gv, tmp0, partial, denp,
        mpart, head_w, head_b, (float*)d_out, ticket);
}

// Round 15
// 186.241 us; speedup vs baseline: 1.0802x; 1.0310x over previous
//
#include <hip/hip_runtime.h>
#include <hip/hip_bf16.h>
#include <cmath>
#include <cstdint>

typedef unsigned int u32;
typedef unsigned char u8;
typedef unsigned short ushort;
typedef __attribute__((ext_vector_type(8))) short short8;
typedef __attribute__((ext_vector_type(4))) float f32x4;
typedef __attribute__((ext_vector_type(16))) float f32x16;
typedef __attribute__((ext_vector_type(4))) unsigned short us4;

#define Gn 2048
#define Hd 256
#define CSTRIDE 192

static __device__ __forceinline__ ushort f2bf(float x) {
    __hip_bfloat16 b = __float2bfloat16(x);
    return *reinterpret_cast<ushort*>(&b);
}
static __device__ __forceinline__ float bf2f(ushort u) {
    return __uint_as_float(((u32)u) << 16);
}

// ===========================================================================
// Weight arenas are FRAGMENT-MAJOR: element (col,k) of W^T lives at
// slot*65536 + ((col>>4)*8 + (k>>5))*512 + (((k&31)>>3)*16 + (col&15))*8
// + (k&7). A wave's MFMA B-fragment (16 cols x 32 k) is one contiguous 1KB
// burst: lane l reads [base + l*8 .. +8).
// R15 = exact revert to the measured-best R12 configuration (186 us):
// 11 dispatches, fp32-A GEMMs with in-loop split + fused LN, ticket finisher.
// ===========================================================================

// ===========================================================================
// GEMM body: bf16x3 split-precision MFMA, 32x64 tile, 2 waves.
// LNF: LayerNorm(+LNRELU) applied to A rows on the fly (exact fp32).
// WRA: (by==0 && bz==0) blocks write normalized A rows to Aout.
// OUTMODE 1 = QKV bf16 epilogue (Q pre-scaled 1/sqrt(32)*log2e).
// QKVMODE 1 (M): V row-layout; QKVMODE 2 (S): V transposed.
// KT=512: ks>=8 reads slot2 arena (fused dual-Wo accumulate).
// ===========================================================================
template <int BETA, int OUTMODE, int QKVMODE, int KT, int LNF, int LNRELU, int WRA>
static __device__ __forceinline__ void gemm_body(
    const int bx, const int by, const int bz,
    const float* __restrict__ A, int lda,
    const ushort* __restrict__ bt_hi, const ushort* __restrict__ bt_lo,
    int slot0, int slot2, const float* __restrict__ bias,
    const float* __restrict__ lng, const float* __restrict__ lnb,
    float* __restrict__ C, int N, float* __restrict__ Aout)
{
    const int tid = threadIdx.x;
    const int wv = tid >> 6, l = tid & 63;
    const int lr = l & 15, lg = l >> 4;
    const int row = bx * 32 + wv * 16 + lr;
    const int col0 = by * 64;
    int slot = slot0, zq = 0, buf = 0;
    if (QKVMODE == 1) { slot = slot0 + bz + bz / 3; zq = bz % 3; buf = bz / 3; }
    else if (QKVMODE == 2) { slot = slot0 + bz; zq = bz; }
    const ushort* bhb = bt_hi + (long)slot * 65536;
    const ushort* blb = bt_lo + (long)slot * 65536;
    const float* arow = A + (long)row * lda;

    float mean = 0.f, rs = 0.f;
    if (LNF) {
        float s = 0.f, s2 = 0.f;
        #pragma unroll
        for (int ks = 0; ks < 8; ++ks) {
            const float4 a0 = *(const float4*)&arow[ks * 32 + lg * 8];
            const float4 a1 = *(const float4*)&arow[ks * 32 + lg * 8 + 4];
            s  += (a0.x + a0.y) + (a0.z + a0.w) + (a1.x + a1.y) + (a1.z + a1.w);
            s2 += a0.x * a0.x + a0.y * a0.y + a0.z * a0.z + a0.w * a0.w +
                  a1.x * a1.x + a1.y * a1.y + a1.z * a1.z + a1.w * a1.w;
        }
        s += __shfl_xor(s, 16);  s += __shfl_xor(s, 32);
        s2 += __shfl_xor(s2, 16); s2 += __shfl_xor(s2, 32);
        mean = s * (1.f / 256.f);
        rs = rsqrtf(s2 * (1.f / 256.f) - mean * mean + 1e-5f);
    }

    const f32x4 z4 = {0.f, 0.f, 0.f, 0.f};
    f32x4 acc[4] = {z4, z4, z4, z4};

    #pragma unroll
    for (int ks = 0; ks < KT / 32; ++ks) {
        const int k0 = ks * 32;
        const ushort* bh; const ushort* bl; int kbi = ks;
        if (KT == 512 && k0 >= 256) {
            bh = bt_hi + (long)slot2 * 65536;
            bl = bt_lo + (long)slot2 * 65536;
            kbi = ks - 8;
        } else { bh = bhb; bl = blb; }
        float av[8];
        *(float4*)&av[0] = *(const float4*)&arow[k0 + lg * 8];
        *(float4*)&av[4] = *(const float4*)&arow[k0 + lg * 8 + 4];
        if (LNF) {
            float gvv[8], bvv[8];
            *(float4*)&gvv[0] = *(const float4*)&lng[k0 + lg * 8];
            *(float4*)&gvv[4] = *(const float4*)&lng[k0 + lg * 8 + 4];
            *(float4*)&bvv[0] = *(const float4*)&lnb[k0 + lg * 8];
            *(float4*)&bvv[4] = *(const float4*)&lnb[k0 + lg * 8 + 4];
            #pragma unroll
            for (int j = 0; j < 8; ++j) {
                float v = (av[j] - mean) * rs * gvv[j] + bvv[j];
                if (LNRELU) v = fmaxf(v, 0.f);
                av[j] = v;
            }
            if (WRA && by == 0 && bz == 0) {
                *(float4*)&Aout[(long)row * 256 + k0 + lg * 8] = *(float4*)&av[0];
                *(float4*)&Aout[(long)row * 256 + k0 + lg * 8 + 4] = *(float4*)&av[4];
            }
        }
        short8 ahi, alo;
        #pragma unroll
        for (int j = 0; j < 8; ++j) {
            const u32 bi = __float_as_uint(av[j]);
            ahi[j] = (short)(bi >> 16);
            const float fh = __uint_as_float(bi & 0xffff0000u);
            alo[j] = (short)f2bf(av[j] - fh);
        }
        #pragma unroll
        for (int f = 0; f < 4; ++f) {
            const long bo = (long)(((by * 4 + f) * 8 + kbi) << 9) + (l << 3);
            const short8 bhi = *(const short8*)&bh[bo];
            const short8 blo = *(const short8*)&bl[bo];
            acc[f] = __builtin_amdgcn_mfma_f32_16x16x32_bf16(ahi, bhi, acc[f], 0, 0, 0);
            acc[f] = __builtin_amdgcn_mfma_f32_16x16x32_bf16(alo, bhi, acc[f], 0, 0, 0);
            acc[f] = __builtin_amdgcn_mfma_f32_16x16x32_bf16(ahi, blo, acc[f], 0, 0, 0);
        }
    }

    const float QS = 0.17677669529663687f * 1.4426950408889634f;

    #pragma unroll
    for (int f = 0; f < 4; ++f) {
        const int col = col0 + f * 16 + lr;
        const float bv = bias ? bias[col] : 0.f;
        #pragma unroll
        for (int r = 0; r < 4; ++r) {
            const int rr = bx * 32 + wv * 16 + lg * 4 + r;
            float v = acc[f][r] + bv;
            if (OUTMODE == 1) {
                if (zq == 0) v *= QS;
                ushort* ob = (ushort*)C + (long)buf * 1572864;
                const int h = col >> 5, d = col & 31;
                if (QKVMODE == 1 || zq < 2)
                    ob[zq * 524288 + ((h * 2048 + rr) << 5) + d] = f2bf(v);
                else
                    ob[1048576 + ((h * 32 + d) << 11) + rr] = f2bf(v);
            } else {
                if (BETA) v += C[(long)rr * N + col];
                C[(long)rr * N + col] = v;
            }
        }
    }
}

// ===========================================================================
// Merged A (256 thr, grid 192): blocks 0-63 mask-dtype detect; blocks 64-191
// weight pre-split (fragment-major). Block 0 also zeroes the wsum ticket.
// ===========================================================================
__global__ __launch_bounds__(256) void mergedA_kernel(
    const u8* __restrict__ adj, int* __restrict__ det0, int* __restrict__ det1,
    const float* __restrict__ pre_w1, const float* __restrict__ pre_w2,
    const float* __restrict__ wm, const float* __restrict__ wsw,
    const float* __restrict__ gate_w1, const float* __restrict__ tr_w,
    ushort* __restrict__ bt_hi, ushort* __restrict__ bt_lo,
    u32* __restrict__ ticket)
{
    __shared__ float T[32][257];
    __shared__ int sd0[4], sd1[4];
    const int tid = threadIdx.x;
    if (blockIdx.x == 0 && tid == 0) *ticket = 0;
    if (blockIdx.x < 64) {
        const int idx = blockIdx.x * 256 + tid;
        const uint4 w = ((const uint4*)adj)[idx];
        int c0 = ((w.x & 0xffu) ? 1 : 0) + ((w.y & 0xffu) ? 1 : 0) +
                 ((w.z & 0xffu) ? 1 : 0) + ((w.w & 0xffu) ? 1 : 0);
        int c1 = ((w.x & 0xffffff00u) ? 1 : 0) + ((w.y & 0xffffff00u) ? 1 : 0) +
                 ((w.z & 0xffffff00u) ? 1 : 0) + ((w.w & 0xffffff00u) ? 1 : 0);
        #pragma unroll
        for (int o = 1; o < 64; o <<= 1) { c0 += __shfl_xor(c0, o); c1 += __shfl_xor(c1, o); }
        if ((tid & 63) == 0) { sd0[tid >> 6] = c0; sd1[tid >> 6] = c1; }
        __syncthreads();
        if (tid == 0) {
            det0[blockIdx.x] = sd0[0] + sd0[1] + sd0[2] + sd0[3];
            det1[blockIdx.x] = sd1[0] + sd1[1] + sd1[2] + sd1[3];
        }
        return;
    }
    const int b2 = blockIdx.x - 64;
    const int slot = b2 >> 3;
    const int kb = b2 & 7;
    const int k0 = kb * 32;
    const float* src; int ncols = 256;
    if (slot == 0) src = pre_w1;
    else if (slot == 1) src = pre_w2;
    else if (slot < 6) src = wm + (long)(slot - 2) * 65536;
    else if (slot < 10) src = wm + (long)(4 + slot - 6) * 65536;
    else if (slot < 14) src = wsw + (long)(slot - 10) * 65536;
    else if (slot == 14) { src = gate_w1; ncols = 128; }
    else src = tr_w;

    const int lsh = (ncols == 256) ? 6 : 5;
    const int tot = 32 << lsh;
    for (int i = tid; i < tot; i += 256) {
        const int kk = i >> lsh, c4 = (i & ((1 << lsh) - 1)) << 2;
        const float4 v = *(const float4*)&src[(long)(k0 + kk) * ncols + c4];
        T[kk][c4 + 0] = v.x; T[kk][c4 + 1] = v.y;
        T[kk][c4 + 2] = v.z; T[kk][c4 + 3] = v.w;
    }
    __syncthreads();
    if (tid < ncols) {
        ushort hb[32], lb[32];
        #pragma unroll
        for (int kk = 0; kk < 32; ++kk) {
            const float x = T[kk][tid];
            const u32 bi = __float_as_uint(x);
            const ushort h = (ushort)(bi >> 16);
            const float fh = __uint_as_float(bi & 0xffff0000u);
            hb[kk] = h; lb[kk] = f2bf(x - fh);
        }
        const int cb = tid >> 4, lr = tid & 15;
        const long base = (long)slot * 65536 + ((cb * 8 + kb) << 9);
        ushort* oh = bt_hi + base;
        ushort* ol = bt_lo + base;
        #pragma unroll
        for (int lg2 = 0; lg2 < 4; ++lg2) {
            const int off = (lg2 * 16 + lr) << 3;
            *(uint4*)&oh[off] = *(const uint4*)&hb[lg2 * 8];
            *(uint4*)&ol[off] = *(const uint4*)&lb[lg2 * 8];
        }
    }
}

// ===========================================================================
// Merged B (128 thr, grid 2304): blocks 0-2047 pack masks AND build CSR for
// their 2 rows (LDS-staged words; threads 0-1 enumerate after barrier);
// blocks 2048-2303 preGEMM1 (tmp0 = gene_emb @ pre_w1 + b1).
// ===========================================================================
__global__ __launch_bounds__(128) void mergedB_kernel(
    const u8* __restrict__ src0, const u8* __restrict__ src1,
    const int* __restrict__ det0, const int* __restrict__ det1,
    u32* __restrict__ bits, int* __restrict__ deg, int* __restrict__ colidx,
    const float* __restrict__ gene_emb,
    const ushort* __restrict__ bt_hi, const ushort* __restrict__ bt_lo,
    const float* __restrict__ pre_b1, float* __restrict__ tmp0)
{
    __shared__ u32 sw[128];
    const int tid = threadIdx.x;
    if (blockIdx.x < 2048) {
        const int lane = tid & 63;
        int c0 = det0[lane], c1 = det1[lane];
        #pragma unroll
        for (int o = 1; o < 64; o <<= 1) { c0 += __shfl_xor(c0, o); c1 += __shfl_xor(c1, o); }
        const int f = (c0 > 0) ? ((c1 > 0) ? 1 : 0) : 2;
        const int W = blockIdx.x * 128 + tid;
        const int z = W >> 17;
        const int rem = W & 131071;
        const int row = rem >> 6, w = rem & 63;
        const u8* src = z ? src1 : src0;
        u32 v = 0;
        if (f == 1) {
            const uint4* p = (const uint4*)(src + (long)row * 2048 + w * 32);
            const uint4 q0 = p[0], q1 = p[1];
            const u32 ws8[8] = {q0.x, q0.y, q0.z, q0.w, q1.x, q1.y, q1.z, q1.w};
            #pragma unroll
            for (int j = 0; j < 8; ++j) {
                const u32 x = ws8[j];
                const u32 m = (((x & 0x7f7f7f7fu) + 0x7f7f7f7fu) | x) & 0x80808080u;
                const u32 b4 = ((m >> 7) & 1u) | ((m >> 14) & 2u) |
                               ((m >> 21) & 4u) | ((m >> 28) & 8u);
                v |= b4 << (j * 4);
            }
        } else if (f == 0) {
            const uint4* p = (const uint4*)((const int*)src + (long)row * 2048 + w * 32);
            #pragma unroll
            for (int j = 0; j < 8; ++j) {
                const uint4 q = p[j];
                v |= (q.x ? 1u : 0u) << (j * 4 + 0);
                v |= (q.y ? 1u : 0u) << (j * 4 + 1);
                v |= (q.z ? 1u : 0u) << (j * 4 + 2);
                v |= (q.w ? 1u : 0u) << (j * 4 + 3);
            }
        } else {
            const uint4* p = (const uint4*)((const float*)src + (long)row * 2048 + w * 32);
            #pragma unroll
            for (int j = 0; j < 8; ++j) {
                const uint4 q = p[j];
                v |= ((q.x & 0x7fffffffu) ? 1u : 0u) << (j * 4 + 0);
                v |= ((q.y & 0x7fffffffu) ? 1u : 0u) << (j * 4 + 1);
                v |= ((q.z & 0x7fffffffu) ? 1u : 0u) << (j * 4 + 2);
                v |= ((q.w & 0x7fffffffu) ? 1u : 0u) << (j * 4 + 3);
            }
        }
        bits[(long)z * 131072 + rem] = v;
        sw[tid] = v;
        __syncthreads();
        if (tid < 2) {
            const int rem0 = (blockIdx.x * 128) & 131071;
            const int r = (rem0 >> 6) + tid;
            int* ci = colidx + ((long)z * 2048 + r) * CSTRIDE;
            int d = 0;
            #pragma unroll 4
            for (int ww = 0; ww < 64; ++ww) {
                u32 x = sw[tid * 64 + ww];
                while (x) {
                    const int j = __ffs(x) - 1;
                    if (d < CSTRIDE) ci[d] = ww * 32 + j;
                    ++d;
                    x &= x - 1;
                }
            }
            deg[z * 2048 + r] = d < CSTRIDE ? d : CSTRIDE;
        }
        return;
    }
    const int b2 = blockIdx.x - 2048;
    gemm_body<0, 0, 0, 256, 0, 0, 0>(b2 >> 2, b2 & 3, 0, gene_emb, 256,
                                     bt_hi, bt_lo, 0, 0, pre_b1,
                                     nullptr, nullptr, tmp0, 256, nullptr);
}

// ===========================================================================
// Merged C (128 thr, grid 256): preGEMM2 with LN1+relu fused on A
// (tmp1 = relu(LN(tmp0))@w2+b2).
// ===========================================================================
__global__ __launch_bounds__(128) void mergedC_kernel(
    const float* __restrict__ tmp0,
    const ushort* __restrict__ bt_hi, const ushort* __restrict__ bt_lo,
    const float* __restrict__ pre_b2, const float* __restrict__ pre_ln_g,
    const float* __restrict__ pre_ln_b, float* __restrict__ tmp1)
{
    const int b2 = blockIdx.x;
    gemm_body<0, 0, 0, 256, 1, 1, 0>(b2 >> 2, b2 & 3, 0, tmp0, 256,
                                     bt_hi, bt_lo, 1, 0, pre_b2,
                                     pre_ln_g, pre_ln_b, tmp1, 256, nullptr);
}

// GEMM wrappers ------------------------------------------------------------
__global__ __launch_bounds__(128) void qkvm_kernel(
    const float* __restrict__ tmp1,
    const ushort* __restrict__ bt_hi, const ushort* __restrict__ bt_lo,
    const float* __restrict__ pre_ln_g, const float* __restrict__ pre_ln_b,
    float* __restrict__ qkvb, float* __restrict__ xg1)
{
    gemm_body<0, 1, 1, 256, 1, 1, 1>(blockIdx.x, blockIdx.y, blockIdx.z,
                                     tmp1, 256, bt_hi, bt_lo, 2, 0, nullptr,
                                     pre_ln_g, pre_ln_b, qkvb, 256, xg1);
}
__global__ __launch_bounds__(128) void wo_m_kernel(
    const float* __restrict__ ctx2,
    const ushort* __restrict__ bt_hi, const ushort* __restrict__ bt_lo,
    float* __restrict__ xg1)
{
    gemm_body<1, 0, 0, 512, 0, 0, 0>(blockIdx.x, blockIdx.y, 0, ctx2, 512,
                                     bt_hi, bt_lo, 5, 9, nullptr,
                                     nullptr, nullptr, xg1, 256, nullptr);
}
__global__ __launch_bounds__(128) void qkvs_kernel(
    const float* __restrict__ xg1,
    const ushort* __restrict__ bt_hi, const ushort* __restrict__ bt_lo,
    float* __restrict__ qkvb)
{
    gemm_body<0, 1, 2, 256, 0, 0, 0>(blockIdx.x, blockIdx.y, blockIdx.z,
                                     xg1, 256, bt_hi, bt_lo, 10, 0, nullptr,
                                     nullptr, nullptr, qkvb, 256, nullptr);
}
__global__ __launch_bounds__(128) void wo_s_kernel(
    const float* __restrict__ ctx2,
    const ushort* __restrict__ bt_hi, const ushort* __restrict__ bt_lo,
    float* __restrict__ xg1)
{
    gemm_body<1, 0, 0, 256, 0, 0, 0>(blockIdx.x, blockIdx.y, 0, ctx2, 512,
                                     bt_hi, bt_lo, 13, 0, nullptr,
                                     nullptr, nullptr, xg1, 256, nullptr);
}

// ===========================================================================
// Sparse masked attention (M block), exp2 domain. One wave per (row, graph).
// ===========================================================================
__global__ __launch_bounds__(64) void attn_sparse_kernel(
    const ushort* __restrict__ qkvb, const int* __restrict__ deg,
    const int* __restrict__ colidx, float* __restrict__ ctx)
{
    const int r = blockIdx.x, z = blockIdx.y;
    const ushort* qb = qkvb + (long)z * 1572864;
    const ushort* kb = qb + 524288;
    const ushort* vr = qb + 1048576;
    const int l = threadIdx.x;
    const int h = l >> 3, dg = l & 7;
    float* orow = &ctx[(long)r * 512 + z * 256 + h * 32 + dg * 4];
    const int n = deg[z * 2048 + r];
    if (n == 0) {
        float a0 = 0.f, a1 = 0.f, a2 = 0.f, a3 = 0.f;
        for (int k = 0; k < 2048; ++k) {
            const us4 vv = *(const us4*)&vr[((h * 2048 + k) << 5) + dg * 4];
            a0 += bf2f(vv[0]); a1 += bf2f(vv[1]); a2 += bf2f(vv[2]); a3 += bf2f(vv[3]);
        }
        float4 o; const float inv = 1.f / 2048.f;
        o.x = a0 * inv; o.y = a1 * inv; o.z = a2 * inv; o.w = a3 * inv;
        *(float4*)orow = o;
        return;
    }
    float q0, q1, q2, q3;
    {
        const us4 qv = *(const us4*)&qb[((h * 2048 + r) << 5) + dg * 4];
        q0 = bf2f(qv[0]); q1 = bf2f(qv[1]); q2 = bf2f(qv[2]); q3 = bf2f(qv[3]);
    }
    const int* ci = colidx + ((long)z * 2048 + r) * CSTRIDE;
    float m = -INFINITY, lsum = 0.f;
    float a0 = 0.f, a1 = 0.f, a2 = 0.f, a3 = 0.f;
    int kn = ci[0];
    us4 kv = *(const us4*)&kb[((h * 2048 + kn) << 5) + dg * 4];
    us4 vv = *(const us4*)&vr[((h * 2048 + kn) << 5) + dg * 4];
    for (int e = 0; e < n; ++e) {
        const us4 kc = kv, vc = vv;
        if (e + 1 < n) {
            kn = ci[e + 1];
            kv = *(const us4*)&kb[((h * 2048 + kn) << 5) + dg * 4];
            vv = *(const us4*)&vr[((h * 2048 + kn) << 5) + dg * 4];
        }
        float s = q0 * bf2f(kc[0]) + q1 * bf2f(kc[1]) +
                  q2 * bf2f(kc[2]) + q3 * bf2f(kc[3]);
        s += __shfl_xor(s, 1); s += __shfl_xor(s, 2); s += __shfl_xor(s, 4);
        const float mn = fmaxf(m, s);
        const float fac = __builtin_amdgcn_exp2f(m - mn);
        const float p = __builtin_amdgcn_exp2f(s - mn);
        lsum = lsum * fac + p;
        a0 = a0 * fac + p * bf2f(vc[0]);
        a1 = a1 * fac + p * bf2f(vc[1]);
        a2 = a2 * fac + p * bf2f(vc[2]);
        a3 = a3 * fac + p * bf2f(vc[3]);
        m = mn;
    }
    const float inv = 1.f / lsum;
    float4 o; o.x = a0 * inv; o.y = a1 * inv; o.z = a2 * inv; o.w = a3 * inv;
    *(float4*)orow = o;
}

// ===========================================================================
// Dense attention (S block): 32x32x16 swapped MFMA, in-register P via
// cvt_pk_bf16 + permlane32_swap, exp2 domain, k-split x8 (512 threads).
// Parallel 8-way merge (acc padded [8][64][17]); padded-LDS coalesced store.
// ===========================================================================
__global__ __launch_bounds__(512) void attn_dense_kernel(
    const ushort* __restrict__ qkvb, float* __restrict__ ctx)
{
    const ushort* qb = qkvb;
    const ushort* kb = qb + 524288;
    const ushort* vt = qb + 1048576;
    const int h = blockIdx.x, qt = blockIdx.y;
    const int wv = threadIdx.x >> 6;
    const int l = threadIdx.x & 63;
    const int lq = l & 31;
    const int hi = l >> 5;
    const int qglob = qt * 32 + lq;

    __shared__ float Mm[8][32], Ml[8][32];
    __shared__ float Macc[8][64][17];
    __shared__ float ctile[32][33];

    const int qoff = ((h * 2048 + qglob) << 5) + hi * 8;
    const short8 qf0 = *(const short8*)&qb[qoff];
    const short8 qf1 = *(const short8*)&qb[qoff + 16];

    float m = -INFINITY, lsum = 0.f;
    f32x16 acc, zz16;
    #pragma unroll
    for (int i = 0; i < 16; ++i) { acc[i] = 0.f; zz16[i] = 0.f; }

    const int kt0 = wv * 256;
    #pragma unroll 2
    for (int it = 0; it < 8; ++it) {
        const int kbase = kt0 + it * 32;
        const int koff = ((h * 2048 + kbase + lq) << 5) + hi * 8;
        const short8 kf0 = *(const short8*)&kb[koff];
        const short8 kf1 = *(const short8*)&kb[koff + 16];
        f32x16 s = __builtin_amdgcn_mfma_f32_32x32x16_bf16(kf0, qf0, zz16, 0, 0, 0);
        s = __builtin_amdgcn_mfma_f32_32x32x16_bf16(kf1, qf1, s, 0, 0, 0);
        float sc[16];
        #pragma unroll
        for (int i = 0; i < 16; ++i) sc[i] = s[i];
        float t[8];
        #pragma unroll
        for (int i = 0; i < 8; ++i) t[i] = fmaxf(sc[i], sc[i + 8]);
        #pragma unroll
        for (int i = 0; i < 4; ++i) t[i] = fmaxf(t[i], t[i + 4]);
        float mt = fmaxf(fmaxf(t[0], t[1]), fmaxf(t[2], t[3]));
        mt = fmaxf(mt, __shfl_xor(mt, 32));
        const float mn = fmaxf(m, mt);
        if (__ballot(mn != m)) {
            const float fac = __builtin_amdgcn_exp2f(m - mn);
            lsum *= fac;
            #pragma unroll
            for (int i = 0; i < 16; ++i) acc[i] *= fac;
            m = mn;
        }
        #pragma unroll
        for (int i = 0; i < 16; ++i) sc[i] = __builtin_amdgcn_exp2f(sc[i] - m);
        #pragma unroll
        for (int i = 0; i < 8; ++i) t[i] = sc[i] + sc[i + 8];
        #pragma unroll
        for (int i = 0; i < 4; ++i) t[i] = t[i] + t[i + 4];
        float ps = (t[0] + t[1]) + (t[2] + t[3]);
        ps += __shfl_xor(ps, 32);
        lsum += ps;
        u32 pk[8];
        #pragma unroll
        for (int g = 0; g < 4; ++g) {
            asm("v_cvt_pk_bf16_f32 %0, %1, %2"
                : "=v"(pk[2 * g]) : "v"(sc[4 * g + 0]), "v"(sc[4 * g + 1]));
            asm("v_cvt_pk_bf16_f32 %0, %1, %2"
                : "=v"(pk[2 * g + 1]) : "v"(sc[4 * g + 2]), "v"(sc[4 * g + 3]));
        }
        asm volatile("v_permlane32_swap_b32 %0, %1" : "+v"(pk[0]), "+v"(pk[2]));
        asm volatile("v_permlane32_swap_b32 %0, %1" : "+v"(pk[1]), "+v"(pk[3]));
        asm volatile("v_permlane32_swap_b32 %0, %1" : "+v"(pk[4]), "+v"(pk[6]));
        asm volatile("v_permlane32_swap_b32 %0, %1" : "+v"(pk[5]), "+v"(pk[7]));
        short8 pB0, pB1;
        ((u32*)&pB0)[0] = pk[0]; ((u32*)&pB0)[1] = pk[1];
        ((u32*)&pB0)[2] = pk[2]; ((u32*)&pB0)[3] = pk[3];
        ((u32*)&pB1)[0] = pk[4]; ((u32*)&pB1)[1] = pk[5];
        ((u32*)&pB1)[2] = pk[6]; ((u32*)&pB1)[3] = pk[7];
        const int voff = ((h * 32 + lq) << 11) + kbase + hi * 8;
        const short8 vf0 = *(const short8*)&vt[voff];
        const short8 vf1 = *(const short8*)&vt[voff + 16];
        acc = __builtin_amdgcn_mfma_f32_32x32x16_bf16(vf0, pB0, acc, 0, 0, 0);
        acc = __builtin_amdgcn_mfma_f32_32x32x16_bf16(vf1, pB1, acc, 0, 0, 0);
    }

    // ---- parallel merge: all waves dump, 512 threads merge (q, d) pairs
    if (l < 32) { Mm[wv][l] = m; Ml[wv][l] = lsum; }
    #pragma unroll
    for (int i = 0; i < 16; ++i) Macc[wv][l][i] = acc[i];
    __syncthreads();
    {
        const int t = threadIdx.x;
        const int q = t & 31, j = t >> 5;    // j in 0..15
        float M = Mm[0][q];
        #pragma unroll
        for (int w = 1; w < 8; ++w) M = fmaxf(M, Mm[w][q]);
        float fw[8], den = 0.f;
        #pragma unroll
        for (int w = 0; w < 8; ++w) {
            fw[w] = __builtin_amdgcn_exp2f(Mm[w][q] - M);
            den += Ml[w][q] * fw[w];
        }
        const float inv = 1.f / den;
        #pragma unroll
        for (int half = 0; half < 2; ++half) {
            const int d = j + 16 * half;
            const int i = (d & 3) | ((d >> 3) << 2);
            const int h2 = (d >> 2) & 1;
            float o = 0.f;
            #pragma unroll
            for (int w = 0; w < 8; ++w) o += Macc[w][h2 * 32 + q][i] * fw[w];
            ctile[d][q] = o * inv;
        }
    }
    __syncthreads();
    if (threadIdx.x < 256) {
        const int t = threadIdx.x;
        const int q = t >> 3, d0 = (t & 7) << 2;
        float4 ov;
        ov.x = ctile[d0 + 0][q]; ov.y = ctile[d0 + 1][q];
        ov.z = ctile[d0 + 2][q]; ov.w = ctile[d0 + 3][q];
        *(float4*)&ctx[(long)(qt * 32 + q) * 512 + h * 32 + d0] = ov;
    }
}

// ===========================================================================
// Aggregation GEMM with LN3 fused on A (=xg1, no relu): y<8 -> t tile;
// y==8 -> gate fully in-register (no atomics; flash merge downstream).
// ===========================================================================
__global__ __launch_bounds__(64) void aggr_gemm_kernel(
    const float* __restrict__ xg1,
    const ushort* __restrict__ bt_hi, const ushort* __restrict__ bt_lo,
    const float* __restrict__ ln_g, const float* __restrict__ ln_b,
    const float* __restrict__ tr_b, const float* __restrict__ g_b1,
    const float* __restrict__ g_w2, const float* __restrict__ g_b2,
    float* __restrict__ t_out, float* __restrict__ gv)
{
    const int l = threadIdx.x;
    const int lr = l & 15, lg = l >> 4;
    const int row0 = blockIdx.x * 16;
    const int gate = (blockIdx.y == 8);
    const int slot = gate ? 14 : 15;
    const int col0 = gate ? 0 : blockIdx.y * 32;
    const int NF = gate ? 8 : 2;
    const ushort* bh0 = bt_hi + (long)slot * 65536;
    const ushort* bl0 = bt_lo + (long)slot * 65536;
    const float* arow = xg1 + (long)(row0 + lr) * 256;

    float s = 0.f, s2 = 0.f;
    #pragma unroll
    for (int ks = 0; ks < 8; ++ks) {
        const float4 a0 = *(const float4*)&arow[ks * 32 + lg * 8];
        const float4 a1 = *(const float4*)&arow[ks * 32 + lg * 8 + 4];
        s  += (a0.x + a0.y) + (a0.z + a0.w) + (a1.x + a1.y) + (a1.z + a1.w);
        s2 += a0.x * a0.x + a0.y * a0.y + a0.z * a0.z + a0.w * a0.w +
              a1.x * a1.x + a1.y * a1.y + a1.z * a1.z + a1.w * a1.w;
    }
    s += __shfl_xor(s, 16);  s += __shfl_xor(s, 32);
    s2 += __shfl_xor(s2, 16); s2 += __shfl_xor(s2, 32);
    const float mean = s * (1.f / 256.f);
    const float rs = rsqrtf(s2 * (1.f / 256.f) - mean * mean + 1e-5f);

    const f32x4 z4 = {0.f, 0.f, 0.f, 0.f};
    f32x4 acc[8] = {z4, z4, z4, z4, z4, z4, z4, z4};

    #pragma unroll
    for (int ks = 0; ks < 8; ++ks) {
        const int k0 = ks * 32;
        float av[8], gvv[8], bvv[8];
        *(float4*)&av[0] = *(const float4*)&arow[k0 + lg * 8];
        *(float4*)&av[4] = *(const float4*)&arow[k0 + lg * 8 + 4];
        *(float4*)&gvv[0] = *(const float4*)&ln_g[k0 + lg * 8];
        *(float4*)&gvv[4] = *(const float4*)&ln_g[k0 + lg * 8 + 4];
        *(float4*)&bvv[0] = *(const float4*)&ln_b[k0 + lg * 8];
        *(float4*)&bvv[4] = *(const float4*)&ln_b[k0 + lg * 8 + 4];
        short8 ahi, alo;
        #pragma unroll
        for (int j = 0; j < 8; ++j) {
            const float vn = (av[j] - mean) * rs * gvv[j] + bvv[j];
            const u32 bi = __float_as_uint(vn);
            ahi[j] = (short)(bi >> 16);
            const float fh = __uint_as_float(bi & 0xffff0000u);
            alo[j] = (short)f2bf(vn - fh);
        }
        for (int f = 0; f < NF; ++f) {
            const int cb = gate ? f : ((int)blockIdx.y * 2 + f);
            const long bo = (long)((cb * 8 + ks) << 9) + (l << 3);
            const short8 bhi = *(const short8*)&bh0[bo];
            const short8 blo = *(const short8*)&bl0[bo];
            acc[f] = __builtin_amdgcn_mfma_f32_16x16x32_bf16(ahi, bhi, acc[f], 0, 0, 0);
            acc[f] = __builtin_amdgcn_mfma_f32_16x16x32_bf16(alo, bhi, acc[f], 0, 0, 0);
            acc[f] = __builtin_amdgcn_mfma_f32_16x16x32_bf16(ahi, blo, acc[f], 0, 0, 0);
        }
    }

    if (!gate) {
        #pragma unroll
        for (int f = 0; f < 2; ++f) {
            const int col = col0 + f * 16 + lr;
            const float bv = tr_b[col];
            #pragma unroll
            for (int r = 0; r < 4; ++r) {
                const int rr = row0 + lg * 4 + r;
                t_out[(long)rr * 256 + col] = fmaxf(acc[f][r] + bv, 0.f);
            }
        }
    } else {
        float b1v[8], w2v[8];
        #pragma unroll
        for (int f = 0; f < 8; ++f) {
            b1v[f] = g_b1[f * 16 + lr];
            w2v[f] = g_w2[f * 16 + lr];
        }
        const float b2 = g_b2[0];
        #pragma unroll
        for (int r = 0; r < 4; ++r) {
            float t = 0.f;
            #pragma unroll
            for (int f = 0; f < 8; ++f)
                t += fmaxf(acc[f][r] + b1v[f], 0.f) * w2v[f];
            #pragma unroll
            for (int o = 1; o < 16; o <<= 1) t += __shfl_xor(t, o);
            if (lr == 0) gv[row0 + lg * 4 + r] = t + b2;
        }
    }
}

// ===========================================================================
// wsum + head (last-block finisher): partial[b][col] over 32 rows with
// per-block local max (flash); the last block (ticket) merges all 64
// partials exactly and computes out = pooled @ head_w + head_b.
// ===========================================================================
__global__ __launch_bounds__(256) void wsum_head_kernel(
    const float* __restrict__ gv, const float* __restrict__ t,
    float* __restrict__ partial, float* __restrict__ denp, float* __restrict__ mpart,
    const float* __restrict__ hw, const float* __restrict__ hb,
    float* __restrict__ out, u32* __restrict__ ticket)
{
    const float L2E = 1.4426950408889634f;
    const int b = blockIdx.x, tid = threadIdx.x;
    float M = -INFINITY;
    #pragma unroll
    for (int i = 0; i < 32; ++i) M = fmaxf(M, gv[b * 32 + i]);
    float s = 0.f, den = 0.f;
    #pragma unroll 4
    for (int i = 0; i < 32; ++i) {
        const int r = b * 32 + i;
        const float w = __builtin_amdgcn_exp2f((gv[r] - M) * L2E);
        den += w;
        s += w * t[(long)r * 256 + tid];
    }
    partial[b * 256 + tid] = s;
    if (tid == 0) { denp[b] = den; mpart[b] = M; }
    __threadfence();
    __syncthreads();
    __shared__ int lastFlag;
    if (tid == 0) lastFlag = (atomicAdd(ticket, 1u) == 63u) ? 1 : 0;
    __syncthreads();
    if (!lastFlag) return;
    __threadfence();  // acquire: make other blocks' writes visible

    __shared__ float fb[64];
    __shared__ float dtot;
    __shared__ float red0[4], red1[4];
    if (tid < 64) {
        const float mb = mpart[tid];
        float Mg = mb;
        #pragma unroll
        for (int o = 1; o < 64; o <<= 1) Mg = fmaxf(Mg, __shfl_xor(Mg, o));
        const float f = __builtin_amdgcn_exp2f((mb - Mg) * L2E);
        fb[tid] = f;
        float dv = f * denp[tid];
        #pragma unroll
        for (int o = 1; o < 64; o <<= 1) dv += __shfl_xor(dv, o);
        if (tid == 0) dtot = dv;
    }
    __syncthreads();
    float p = 0.f;
    #pragma unroll 8
    for (int bb = 0; bb < 64; ++bb) p += fb[bb] * partial[bb * 256 + tid];
    p /= dtot;
    float s0 = p * hw[tid * 2 + 0];
    float s1 = p * hw[tid * 2 + 1];
    #pragma unroll
    for (int o = 1; o < 64; o <<= 1) { s0 += __shfl_xor(s0, o); s1 += __shfl_xor(s1, o); }
    if ((tid & 63) == 0) { red0[tid >> 6] = s0; red1[tid >> 6] = s1; }
    __syncthreads();
    if (tid == 0) {
        out[0] = red0[0] + red0[1] + red0[2] + red0[3] + hb[0];
        out[1] = red1[0] + red1[1] + red1[2] + red1[3] + hb[1];
    }
}

// ---------------------------------------------------------------------------
extern "C" void kernel_launch(void* const* d_in, const int* in_sizes, int n_in,
                              void* d_out, int out_size, void* d_ws, size_t ws_size,
                              hipStream_t stream)
{
    (void)in_sizes; (void)n_in; (void)out_size; (void)ws_size;
    const float* gene_emb = (const float*)d_in[0];
    const float* pre_w1   = (const float*)d_in[3];
    const float* pre_b1   = (const float*)d_in[4];
    const float* pre_w2   = (const float*)d_in[5];
    const float* pre_b2   = (const float*)d_in[6];
    const float* pre_ln_g = (const float*)d_in[7];
    const float* pre_ln_b = (const float*)d_in[8];
    const float* wm       = (const float*)d_in[9];
    const float* wsw      = (const float*)d_in[10];
    const float* ln_g     = (const float*)d_in[11];
    const float* ln_b     = (const float*)d_in[12];
    const float* gate_w1  = (const float*)d_in[13];
    const float* gate_b1  = (const float*)d_in[14];
    const float* gate_w2  = (const float*)d_in[15];
    const float* gate_b2  = (const float*)d_in[16];
    const float* tr_w     = (const float*)d_in[17];
    const float* tr_b     = (const float*)d_in[18];
    const float* head_w   = (const float*)d_in[19];
    const float* head_b   = (const float*)d_in[20];
    const u8* adj_pp      = (const u8*)d_in[21];
    const u8* adj_rr      = (const u8*)d_in[22];
    // d_in[1],[2],[23],[24] dead (reaction/metab branches never reach output)

    const long NHf = (long)Gn * Hd;
    float* tmp0    = (float*)d_ws;
    float* tmp1    = tmp0 + NHf;
    float* xg1     = tmp1 + NHf;
    float* ctx2    = xg1 + NHf;
    float* gv      = ctx2 + 2 * NHf;
    float* partial = gv + Gn;
    float* denp    = partial + 64 * 256;
    float* mpart   = denp + 64;
    int* det0      = (int*)(mpart + 64);
    int* det1      = det0 + 64;
    u32* ticket    = (u32*)(det1 + 64);
    int* deg       = (int*)(ticket + 64);
    int* colidx    = deg + 4096;
    u32* bits      = (u32*)(colidx + 2L * 2048 * CSTRIDE);
    ushort* qkvb   = (ushort*)(bits + 262144);
    ushort* bt_hi  = qkvb + 2L * 1572864;
    ushort* bt_lo  = bt_hi + 16L * 65536;

    dim3 B256(256), B128(128), T64(64);

    // 1: detect || weight pre-split (also zeroes the wsum ticket)
    mergedA_kernel<<<dim3(192), B256, 0, stream>>>(adj_pp, det0, det1,
        pre_w1, pre_w2, wm, wsw, gate_w1, tr_w, bt_hi, bt_lo, ticket);
    // 2: pack masks + CSR || preGEMM1
    mergedB_kernel<<<dim3(2304), B128, 0, stream>>>(adj_pp, adj_rr, det0, det1,
        bits, deg, colidx, gene_emb, bt_hi, bt_lo, pre_b1, tmp0);
    // 3: preGEMM2 (LN1+relu fused)
    mergedC_kernel<<<dim3(256), B128, 0, stream>>>(tmp0, bt_hi, bt_lo,
        pre_b2, pre_ln_g, pre_ln_b, tmp1);
    // 4: QKV-M (LN2+relu fused; writes xg1)
    qkvm_kernel<<<dim3(64, 4, 6), B128, 0, stream>>>(tmp1, bt_hi, bt_lo,
        pre_ln_g, pre_ln_b, (float*)qkvb, xg1);
    // 5: sparse masked attention
    attn_sparse_kernel<<<dim3(2048, 2), T64, 0, stream>>>(qkvb, deg, colidx, ctx2);
    // 6: fused dual-Wo (K=512)
    wo_m_kernel<<<dim3(64, 4), B128, 0, stream>>>(ctx2, bt_hi, bt_lo, xg1);
    // 7: QKV-S
    qkvs_kernel<<<dim3(64, 4, 3), B128, 0, stream>>>(xg1, bt_hi, bt_lo, (float*)qkvb);
    // 8: dense self-attention (parallel 8-way merge)
    attn_dense_kernel<<<dim3(8, 64), dim3(512), 0, stream>>>(qkvb, ctx2);
    // 9: Wo-S
    wo_s_kernel<<<dim3(64, 4), B128, 0, stream>>>(ctx2, bt_hi, bt_lo, xg1);
    // 10: aggregation GEMM (LN3 fused)
    aggr_gemm_kernel<<<dim3(128, 9), T64, 0, stream>>>(xg1, bt_hi, bt_lo,
        ln_g, ln_b, tr_b, gate_b1, gate_w2, gate_b2, tmp0, gv);
    // 11: weighted sum + head (last-block finisher)
    wsum_head_kernel<<<dim3(64), B256, 0, stream>>>(gv, tmp0, partial, denp,
        mpart, head_w, head_b, (float*)d_out, ticket);
}